// Round 7
// baseline (160.215 us; speedup 1.0000x reference)
//
#include <hip/hip_runtime.h>
#include <math.h>

// Problem constants
#define SS    256      // seq len
#define BB    4        // batch
#define HH    160      // hidden
#define NH_   8        // heads
#define HD_   20       // head dim
#define TBL   1025     // 2*MAXLEN+1
#define MAXL  512
#define FF_   640

// setup-kernel block ranges.  P rows actually used are [257,767] (psi-psj+512
// with psi,psj in [0,256)), so only compute rows [256,768).
#define PT_TILES 64                    // 512 rows / 8
#define PT_PER_TAB (PT_TILES * 3)      // 192
#define PT_END (4 * PT_PER_TAB)        // 768
#define QKV_END (PT_END + 512)         // + (1024/16) x 8
#define WRT_END (QKV_END + 100)        // + 25600/256

// ---------------------------------------------------------------------------
// Mega setup kernel: [0,768) ptab-as-GEMM (rows 256..767); [768,1280) QKV;
// [1280,1380) WrT.  All branches block-uniform.
// ---------------------------------------------------------------------------
__global__ __launch_bounds__(256) void k_setup(
    const float* __restrict__ pe_ss, const float* __restrict__ pe_se,
    const float* __restrict__ pe_es, const float* __restrict__ pe_ee,
    const float* __restrict__ W_fus, const float* __restrict__ b_fus,
    const float* __restrict__ inp,
    const float* __restrict__ Wq, const float* __restrict__ bq,
    const float* __restrict__ Wk, const float* __restrict__ bk,
    const float* __restrict__ Wv, const float* __restrict__ bv,
    const float* __restrict__ Wr,
    float* __restrict__ P, float* __restrict__ qb, float* __restrict__ kb,
    float* __restrict__ vb, float* __restrict__ WrT) {
  int bid = blockIdx.x;
  int t = threadIdx.x;
  __shared__ __align__(16) float As[16][HH];

  if (bid < PT_END) {
    // ---- P tables as tiled GEMM: 8 rows x 64 cols per block ----
    int tab = bid / PT_PER_TAB;
    int rem = bid - tab * PT_PER_TAB;
    int tile = rem / 3, yc = rem - tile * 3;
    int row0 = 256 + tile * 8;          // rows 256..767 only
    const float* pe = (tab == 0) ? pe_ss : (tab == 1) ? pe_se
                    : (tab == 2) ? pe_es : pe_ee;
    for (int idx = t; idx < 8 * 40; idx += 256) {
      int r = idx / 40, c4 = idx - r * 40;
      *(float4*)&As[r][c4 * 4] =
          *(const float4*)(pe + (size_t)(row0 + r) * HH + c4 * 4);
    }
    __syncthreads();
    int c = (t & 63) + yc * 64;
    int wv = t >> 6;
    if (c < HH) {
      float acc0, acc1;
      acc0 = acc1 = (tab == 0) ? b_fus[c] : 0.0f;
      const float* wp = W_fus + (size_t)tab * HH * HH + c;
      int r0 = wv * 2, r1 = wv * 2 + 1;
      #pragma unroll 2
      for (int k = 0; k < HH; k += 8) {
        float w[8];
        #pragma unroll
        for (int q = 0; q < 8; ++q) w[q] = wp[(size_t)(k + q) * HH];
        float4 a0 = *(const float4*)&As[r0][k];
        float4 a1 = *(const float4*)&As[r0][k + 4];
        float4 b0 = *(const float4*)&As[r1][k];
        float4 b1_ = *(const float4*)&As[r1][k + 4];
        acc0 = fmaf(a0.x, w[0], acc0); acc0 = fmaf(a0.y, w[1], acc0);
        acc0 = fmaf(a0.z, w[2], acc0); acc0 = fmaf(a0.w, w[3], acc0);
        acc0 = fmaf(a1.x, w[4], acc0); acc0 = fmaf(a1.y, w[5], acc0);
        acc0 = fmaf(a1.z, w[6], acc0); acc0 = fmaf(a1.w, w[7], acc0);
        acc1 = fmaf(b0.x, w[0], acc1); acc1 = fmaf(b0.y, w[1], acc1);
        acc1 = fmaf(b0.z, w[2], acc1); acc1 = fmaf(b0.w, w[3], acc1);
        acc1 = fmaf(b1_.x, w[4], acc1); acc1 = fmaf(b1_.y, w[5], acc1);
        acc1 = fmaf(b1_.z, w[6], acc1); acc1 = fmaf(b1_.w, w[7], acc1);
      }
      P[((size_t)tab * TBL + row0 + r0) * HH + c] = acc0;
      P[((size_t)tab * TBL + row0 + r1) * HH + c] = acc1;
    }
  } else if (bid < QKV_END) {
    // ---- fused Q/K/V projection: 16 tokens x 64 cols-of-480 ----
    int qbid = bid - PT_END;
    int bx = qbid & 63, by = qbid >> 6;
    int tok0 = bx * 16;
    {
      const float4* src = (const float4*)(inp + (size_t)tok0 * HH);
      float4* dst = (float4*)As;
      for (int idx = t; idx < 16 * HH / 4; idx += 256) dst[idx] = src[idx];
    }
    __syncthreads();
    int col = (t & 63) + by * 64;
    int wv = t >> 6;
    if (col < 480) {
      int mat = col / 160;
      int c = col - mat * 160;
      const float* W   = (mat == 0) ? Wq : (mat == 1) ? Wk : Wv;
      const float* bia = (mat == 0) ? bq : (mat == 1) ? bk : bv;
      float* O         = (mat == 0) ? qb : (mat == 1) ? kb : vb;
      float acc[4];
      float bb = bia[c];
      #pragma unroll
      for (int i = 0; i < 4; ++i) acc[i] = bb;
      const float* wp = W + c;
      #pragma unroll 2
      for (int k = 0; k < HH; k += 8) {
        float w[8];
        #pragma unroll
        for (int q = 0; q < 8; ++q) w[q] = wp[(size_t)(k + q) * HH];
        #pragma unroll
        for (int i = 0; i < 4; ++i) {
          const float4 a0 = *(const float4*)&As[wv * 4 + i][k];
          const float4 a1 = *(const float4*)&As[wv * 4 + i][k + 4];
          acc[i] = fmaf(a0.x, w[0], acc[i]);
          acc[i] = fmaf(a0.y, w[1], acc[i]);
          acc[i] = fmaf(a0.z, w[2], acc[i]);
          acc[i] = fmaf(a0.w, w[3], acc[i]);
          acc[i] = fmaf(a1.x, w[4], acc[i]);
          acc[i] = fmaf(a1.y, w[5], acc[i]);
          acc[i] = fmaf(a1.z, w[6], acc[i]);
          acc[i] = fmaf(a1.w, w[7], acc[i]);
        }
      }
      #pragma unroll
      for (int i = 0; i < 4; ++i)
        O[(size_t)(tok0 + wv * 4 + i) * HH + c] = acc[i];
    }
  } else {
    // ---- WrT[cp][cc] = Wr[cc][cp] ----
    int o = (bid - QKV_END) * 256 + t;
    int cp = o / HH, cc = o - cp * HH;
    WrT[o] = Wr[(size_t)cc * HH + cp];
  }
}

// ---------------------------------------------------------------------------
// Generic tiled GEMM: C[M,N] = op(A[M,KK] @ W[KK,N] + bias)
// ---------------------------------------------------------------------------
template<int TT, int KK, bool RELU>
__global__ __launch_bounds__(256) void k_gemm(
    const float* __restrict__ A, const float* __restrict__ W,
    const float* __restrict__ bias, float* __restrict__ C, int N) {
  const int TPW = TT / 4;
  int tok0 = blockIdx.x * TT;
  int t = threadIdx.x;
  __shared__ __align__(16) float As[TT][KK];
  {
    const float4* src = (const float4*)(A + (size_t)tok0 * KK);
    float4* dst = (float4*)As;
    for (int idx = t; idx < TT * KK / 4; idx += 256) dst[idx] = src[idx];
  }
  __syncthreads();
  int c = (t & 63) + blockIdx.y * 64;
  int wv = t >> 6;
  if (c < N) {
    float acc[TPW];
    float bb = bias ? bias[c] : 0.0f;
    #pragma unroll
    for (int i = 0; i < TPW; ++i) acc[i] = bb;
    const float* wp = W + c;
    #pragma unroll 2
    for (int k = 0; k < KK; k += 8) {
      float w[8];
      #pragma unroll
      for (int q = 0; q < 8; ++q) w[q] = wp[(size_t)(k + q) * N];
      #pragma unroll
      for (int i = 0; i < TPW; ++i) {
        const float4 a0 = *(const float4*)&As[wv * TPW + i][k];
        const float4 a1 = *(const float4*)&As[wv * TPW + i][k + 4];
        acc[i] = fmaf(a0.x, w[0], acc[i]);
        acc[i] = fmaf(a0.y, w[1], acc[i]);
        acc[i] = fmaf(a0.z, w[2], acc[i]);
        acc[i] = fmaf(a0.w, w[3], acc[i]);
        acc[i] = fmaf(a1.x, w[4], acc[i]);
        acc[i] = fmaf(a1.y, w[5], acc[i]);
        acc[i] = fmaf(a1.z, w[6], acc[i]);
        acc[i] = fmaf(a1.w, w[7], acc[i]);
      }
    }
    #pragma unroll
    for (int i = 0; i < TPW; ++i) {
      float v = RELU ? fmaxf(acc[i], 0.0f) : acc[i];
      C[(size_t)(tok0 + wv * TPW + i) * N + c] = v;
    }
  }
}

// ---------------------------------------------------------------------------
// LN1 + W1 + relu fused.
// ---------------------------------------------------------------------------
__global__ __launch_bounds__(256) void k_ffn1(
    const float* __restrict__ Y, const float* __restrict__ g1,
    const float* __restrict__ b1ln, const float* __restrict__ W1,
    const float* __restrict__ b1, float* __restrict__ Hb) {
  const int TT = 16;
  int tok0 = blockIdx.x * TT;
  int t = threadIdx.x;
  __shared__ __align__(16) float As[TT][HH];
  {
    const float4* src = (const float4*)(Y + (size_t)tok0 * HH);
    float4* dst = (float4*)As;
    for (int idx = t; idx < TT * HH / 4; idx += 256) dst[idx] = src[idx];
  }
  __syncthreads();
  {
    int row = t >> 4, l = t & 15;
    float s = 0.0f;
    #pragma unroll
    for (int c = l; c < HH; c += 16) s += As[row][c];
    #pragma unroll
    for (int m = 1; m < 16; m <<= 1) s += __shfl_xor(s, m);
    float mu = s * (1.0f / HH);
    float s2 = 0.0f;
    #pragma unroll
    for (int c = l; c < HH; c += 16) { float d = As[row][c] - mu; s2 = fmaf(d, d, s2); }
    #pragma unroll
    for (int m = 1; m < 16; m <<= 1) s2 += __shfl_xor(s2, m);
    float rstd = rsqrtf(s2 * (1.0f / HH) + 2.5e-6f);  // eps 1e-5 / 4
    #pragma unroll
    for (int c = l; c < HH; c += 16)
      As[row][c] = (As[row][c] - mu) * rstd * g1[c] + b1ln[c];
  }
  __syncthreads();
  int c = (t & 63) + blockIdx.y * 64;
  int wv = t >> 6;
  float acc[4];
  float bb = b1[c];
  #pragma unroll
  for (int i = 0; i < 4; ++i) acc[i] = bb;
  const float* wp = W1 + c;
  #pragma unroll 2
  for (int k = 0; k < HH; k += 8) {
    float w[8];
    #pragma unroll
    for (int q = 0; q < 8; ++q) w[q] = wp[(size_t)(k + q) * FF_];
    #pragma unroll
    for (int i = 0; i < 4; ++i) {
      const float4 a0 = *(const float4*)&As[wv * 4 + i][k];
      const float4 a1 = *(const float4*)&As[wv * 4 + i][k + 4];
      acc[i] = fmaf(a0.x, w[0], acc[i]);
      acc[i] = fmaf(a0.y, w[1], acc[i]);
      acc[i] = fmaf(a0.z, w[2], acc[i]);
      acc[i] = fmaf(a0.w, w[3], acc[i]);
      acc[i] = fmaf(a1.x, w[4], acc[i]);
      acc[i] = fmaf(a1.y, w[5], acc[i]);
      acc[i] = fmaf(a1.z, w[6], acc[i]);
      acc[i] = fmaf(a1.w, w[7], acc[i]);
    }
  }
  #pragma unroll
  for (int i = 0; i < 4; ++i)
    Hb[(size_t)(tok0 + wv * 4 + i) * FF_ + c] = fmaxf(acc[i], 0.0f);
}

// ---------------------------------------------------------------------------
// Fused attention, 512 threads (8 waves) per (b,i) -> 32 waves/CU.
// Wave w owns j in [w*32, w*32+32), 2 passes of 16.  Wave-uniform mask skip:
// passes entirely beyond limit skip gather/A_C.  VGPR must stay <=64
// (launch_bounds(512,8)); R6 body measured 60.
// ---------------------------------------------------------------------------
#define RSTR 164
#define SCS  257

__global__ __launch_bounds__(512, 8) void k_attn(
    const float* __restrict__ qb, const float* __restrict__ kb, const float* __restrict__ vb,
    const float* __restrict__ WrT, const float* __restrict__ P,
    const int* __restrict__ pos_s, const int* __restrict__ pos_e,
    const int* __restrict__ seq_len, const int* __restrict__ lex_num,
    const float* __restrict__ utab, const float* __restrict__ vtab,
    float* __restrict__ attn_out) {
  int blk = blockIdx.x;        // b*S + i
  int b = blk >> 8;
  int i = blk & 255;
  int t = threadIdx.x;
  __shared__ __align__(16) float qu[HH];
  __shared__ __align__(16) float qv_s[HH];
  __shared__ __align__(16) float g_s[NH_][RSTR];
  __shared__ __align__(16) float sc[NH_][SCS];
  __shared__ int ps_s[SS], pe_s[SS];

  if (t < HH) {
    float q = qb[(size_t)blk * HH + t];
    qu[t] = q + utab[t];
    qv_s[t] = q + vtab[t];
  }
  if (t < SS) {
    ps_s[t] = pos_s[b * SS + t];
    pe_s[t] = pos_e[b * SS + t];
  }
  __syncthreads();

  // g[h][cc] = sum_d qv[20h+d] * WrT[(20h+d)*160+cc]
  for (int p = t; p < NH_ * HH; p += 512) {
    int h = p / HH, cc = p - h * HH;
    const float* wp = WrT + (size_t)(h * HD_) * HH + cc;
    float acc = 0.0f;
    #pragma unroll
    for (int d = 0; d < HD_; ++d)
      acc = fmaf(qv_s[h * HD_ + d], wp[(size_t)d * HH], acc);
    g_s[h][cc] = acc;
  }
  __syncthreads();

  int w = t >> 6, lane = t & 63;
  int jj = lane >> 2, cg = lane & 3;
  int psi = ps_s[i], pei = pe_s[i];
  int limit = seq_len[b] + lex_num[0];
  const float scale = 0.22360679774997896f;  // 1/sqrt(20)

  const float4* P40 = (const float4*)P;
  const float4* P41 = P40 + (size_t)TBL * 40;
  const float4* P42 = P41 + (size_t)TBL * 40;
  const float4* P43 = P42 + (size_t)TBL * 40;
  const float4* kb4 = (const float4*)(kb + (size_t)b * SS * HH);

  #pragma unroll
  for (int pass = 0; pass < 2; ++pass) {
    int jbase = w * 32 + pass * 16;
    int j = jbase + jj;
    if (jbase >= limit) {            // wave-uniform: whole tile masked
      sc[2 * cg][j]     = -1.0e15f;
      sc[2 * cg + 1][j] = -1.0e15f;
      continue;
    }
    int psj = ps_s[j], pej = pe_s[j];
    int o0 = (psi - psj + MAXL) * 40 + cg;
    int o1 = (psi - pej + MAXL) * 40 + cg;
    int o2 = (pei - psj + MAXL) * 40 + cg;
    int o3 = (pei - pej + MAXL) * 40 + cg;
    float bd[NH_];
    #pragma unroll
    for (int h = 0; h < NH_; ++h) bd[h] = 0.0f;
    // immediate-consume gather: 4 loads -> relu -> 32 FMAs, per q
    #pragma unroll 2
    for (int q = 0; q < 10; ++q) {
      float4 a0 = P40[o0 + q * 4];
      float4 a1 = P41[o1 + q * 4];
      float4 a2 = P42[o2 + q * 4];
      float4 a3 = P43[o3 + q * 4];
      float rl0 = fmaxf(a0.x + a1.x + a2.x + a3.x, 0.0f);
      float rl1 = fmaxf(a0.y + a1.y + a2.y + a3.y, 0.0f);
      float rl2 = fmaxf(a0.z + a1.z + a2.z + a3.z, 0.0f);
      float rl3 = fmaxf(a0.w + a1.w + a2.w + a3.w, 0.0f);
      int c4 = (q * 4 + cg) * 4;
      #pragma unroll
      for (int h = 0; h < NH_; ++h) {
        float4 g4 = *(const float4*)&g_s[h][c4];
        bd[h] = fmaf(rl0, g4.x, bd[h]);
        bd[h] = fmaf(rl1, g4.y, bd[h]);
        bd[h] = fmaf(rl2, g4.z, bd[h]);
        bd[h] = fmaf(rl3, g4.w, bd[h]);
      }
    }
    // A_C for heads 2cg, 2cg+1 : c in [40cg, 40cg+40)
    float ac0 = 0.0f, ac1 = 0.0f;
    {
      int kbase = j * 40 + 10 * cg;
      #pragma unroll
      for (int m = 0; m < 10; ++m) {
        float4 kv = kb4[kbase + m];
        float4 q4 = *(const float4*)&qu[(10 * cg + m) * 4];
        if (m < 5) {
          ac0 = fmaf(q4.x, kv.x, ac0); ac0 = fmaf(q4.y, kv.y, ac0);
          ac0 = fmaf(q4.z, kv.z, ac0); ac0 = fmaf(q4.w, kv.w, ac0);
        } else {
          ac1 = fmaf(q4.x, kv.x, ac1); ac1 = fmaf(q4.y, kv.y, ac1);
          ac1 = fmaf(q4.z, kv.z, ac1); ac1 = fmaf(q4.w, kv.w, ac1);
        }
      }
    }
    #pragma unroll
    for (int h = 0; h < NH_; ++h) {
      bd[h] += __shfl_xor(bd[h], 1);
      bd[h] += __shfl_xor(bd[h], 2);
    }
    float s0, s1;
    if      (cg == 0) { s0 = bd[0]; s1 = bd[1]; }
    else if (cg == 1) { s0 = bd[2]; s1 = bd[3]; }
    else if (cg == 2) { s0 = bd[4]; s1 = bd[5]; }
    else              { s0 = bd[6]; s1 = bd[7]; }
    bool valid = (j < limit);
    sc[2 * cg][j]     = valid ? (s0 + ac0) * scale : -1.0e15f;
    sc[2 * cg + 1][j] = valid ? (s1 + ac1) * scale : -1.0e15f;
  }
  __syncthreads();

  // softmax: first 256 threads, 8 groups of 32 lanes, one head each
  if (t < 256) {
    int h = t >> 5, l = t & 31;
    float m = -3.0e38f;
    float e[8];
    #pragma unroll
    for (int ii = 0; ii < 8; ++ii) m = fmaxf(m, sc[h][l + ii * 32]);
    #pragma unroll
    for (int msk = 16; msk; msk >>= 1) m = fmaxf(m, __shfl_xor(m, msk));
    float s = 0.0f;
    #pragma unroll
    for (int ii = 0; ii < 8; ++ii) { e[ii] = __expf(sc[h][l + ii * 32] - m); s += e[ii]; }
    #pragma unroll
    for (int msk = 16; msk; msk >>= 1) s += __shfl_xor(s, msk);
    float inv = 1.0f / s;
    #pragma unroll
    for (int ii = 0; ii < 8; ++ii) sc[h][l + ii * 32] = e[ii] * inv;
  }
  __syncthreads();

  // PV: 2 threads per output column; each sums half the (clipped) j range.
  if (t < 2 * HH) {
    int c = t >> 1, half = t & 1;
    int h = c / HD_;
    int jstart = half * 128;
    int jend = min(limit, jstart + 128);
    float acc0 = 0.f, acc1 = 0.f;
    const float* vcol = vb + (size_t)b * SS * HH + c;
    for (int j2 = jstart; j2 + 1 < jend; j2 += 2) {
      acc0 = fmaf(sc[h][j2],     vcol[(size_t)j2 * HH],       acc0);
      acc1 = fmaf(sc[h][j2 + 1], vcol[(size_t)(j2 + 1) * HH], acc1);
    }
    if (((jend - jstart) & 1) && jend > jstart)
      acc0 = fmaf(sc[h][jend - 1], vcol[(size_t)(jend - 1) * HH], acc0);
    float acc = acc0 + acc1;
    acc += __shfl_xor(acc, 1);
    if (half == 0) attn_out[(size_t)blk * HH + c] = acc;
  }
}

// ---------------------------------------------------------------------------
// Final LayerNorm.  LN(y+y) == LN(y) with eps/4.
// ---------------------------------------------------------------------------
__global__ __launch_bounds__(256) void k_ln(
    const float* __restrict__ Y, const float* __restrict__ g,
    const float* __restrict__ bln, float* __restrict__ O) {
  int tok = blockIdx.x * 4 + (threadIdx.x >> 6);
  int l = threadIdx.x & 63;
  const float* y = Y + (size_t)tok * HH;
  float a = y[l];
  float bv = y[l + 64];
  bool has3 = l < (HH - 128);
  float cv = has3 ? y[l + 128] : 0.0f;
  float s = a + bv + cv;
  #pragma unroll
  for (int m = 32; m; m >>= 1) s += __shfl_xor(s, m);
  float mu = s * (1.0f / HH);
  float da = a - mu, db = bv - mu, dc = has3 ? (cv - mu) : 0.0f;
  float s2 = da * da + db * db + dc * dc;
  #pragma unroll
  for (int m = 32; m; m >>= 1) s2 += __shfl_xor(s2, m);
  float rstd = rsqrtf(s2 * (1.0f / HH) + 2.5e-6f);  // eps 1e-5 / 4
  float* o = O + (size_t)tok * HH;
  o[l]      = da * rstd * g[l] + bln[l];
  o[l + 64] = db * rstd * g[l + 64] + bln[l + 64];
  if (has3) o[l + 128] = dc * rstd * g[l + 128] + bln[l + 128];
}

// ---------------------------------------------------------------------------
extern "C" void kernel_launch(void* const* d_in, const int* in_sizes, int n_in,
                              void* d_out, int out_size, void* d_ws, size_t ws_size,
                              hipStream_t stream) {
  const float* inp    = (const float*)d_in[0];
  const int*   pos_s  = (const int*)d_in[1];
  const int*   pos_e  = (const int*)d_in[2];
  const int*   seq_ln = (const int*)d_in[3];
  const int*   lex_nm = (const int*)d_in[4];
  const float* pe_ss  = (const float*)d_in[5];
  const float* pe_se  = (const float*)d_in[6];
  const float* pe_es  = (const float*)d_in[7];
  const float* pe_ee  = (const float*)d_in[8];
  const float* W_fus  = (const float*)d_in[9];
  const float* b_fus  = (const float*)d_in[10];
  const float* Wq     = (const float*)d_in[11];
  const float* bq     = (const float*)d_in[12];
  const float* Wk     = (const float*)d_in[13];
  const float* bk     = (const float*)d_in[14];
  const float* Wv     = (const float*)d_in[15];
  const float* bv     = (const float*)d_in[16];
  const float* Wr     = (const float*)d_in[17];
  // d_in[18] = br : constant-over-j term, cancels in softmax
  const float* utab   = (const float*)d_in[19];
  const float* vtab   = (const float*)d_in[20];
  const float* W_fin  = (const float*)d_in[21];
  const float* b_fin  = (const float*)d_in[22];
  const float* ln1_g  = (const float*)d_in[23];
  const float* ln1_b  = (const float*)d_in[24];
  const float* W1     = (const float*)d_in[25];
  const float* b1     = (const float*)d_in[26];
  const float* W2     = (const float*)d_in[27];
  const float* b2     = (const float*)d_in[28];
  const float* ln2_g  = (const float*)d_in[29];
  const float* ln2_b  = (const float*)d_in[30];

  float* ws = (float*)d_ws;
  float* P        = ws;                        // 4*1025*160 = 656000
  float* qb       = P + 4 * TBL * HH;          // 163840 each
  float* kb       = qb + BB * SS * HH;
  float* vb       = kb + BB * SS * HH;
  float* WrT      = vb + BB * SS * HH;         // 25600
  float* attn_out = WrT + HH * HH;             // 163840
  float* ybuf     = attn_out + BB * SS * HH;   // 163840
  float* hbuf     = ybuf + BB * SS * HH;       // 655360
  float* y2       = hbuf + (size_t)BB * SS * FF_;  // 163840

  (void)in_sizes; (void)n_in; (void)out_size; (void)ws_size;

  const int M = BB * SS;  // 1024

  k_setup<<<WRT_END, 256, 0, stream>>>(pe_ss, pe_se, pe_es, pe_ee, W_fus, b_fus,
                                       inp, Wq, bq, Wk, bk, Wv, bv, Wr,
                                       P, qb, kb, vb, WrT);
  k_attn<<<M, 512, 0, stream>>>(qb, kb, vb, WrT, P, pos_s, pos_e, seq_ln, lex_nm,
                                utab, vtab, attn_out);
  k_gemm<4, HH, false><<<dim3(M / 4, 3), 256, 0, stream>>>(attn_out, W_fin, b_fin, ybuf, HH);
  k_ffn1<<<dim3(M / 16, 10), 256, 0, stream>>>(ybuf, ln1_g, ln1_b, W1, b1, hbuf);
  k_gemm<4, FF_, false><<<dim3(M / 4, 3), 256, 0, stream>>>(hbuf, W2, b2, y2, HH);
  k_ln<<<M / 4, 256, 0, stream>>>(y2, ln2_g, ln2_b, (float*)d_out);
}

// Round 8
// 121.801 us; speedup vs baseline: 1.3154x; 1.3154x over previous
//
#include <hip/hip_runtime.h>
#include <math.h>

// Problem constants
#define SS    256      // seq len
#define BB    4        // batch
#define HH    160      // hidden
#define NH_   8        // heads
#define HD_   20       // head dim
#define TBL   1025     // 2*MAXLEN+1
#define MAXL  512
#define FF_   640

// setup-kernel block ranges.  P rows actually used are [257,767] (psi-psj+512
// with psi,psj in [0,256)), so only compute rows [256,768).
#define PT_TILES 64                    // 512 rows / 8
#define PT_PER_TAB (PT_TILES * 3)      // 192
#define PT_END (4 * PT_PER_TAB)        // 768
#define QKV_END (PT_END + 512)         // + (1024/16) x 8
#define WRT_END (QKV_END + 100)        // + 25600/256

// ---------------------------------------------------------------------------
// Mega setup kernel: [0,768) ptab-as-GEMM (rows 256..767); [768,1280) QKV;
// [1280,1380) WrT.  All branches block-uniform.
// ---------------------------------------------------------------------------
__global__ __launch_bounds__(256) void k_setup(
    const float* __restrict__ pe_ss, const float* __restrict__ pe_se,
    const float* __restrict__ pe_es, const float* __restrict__ pe_ee,
    const float* __restrict__ W_fus, const float* __restrict__ b_fus,
    const float* __restrict__ inp,
    const float* __restrict__ Wq, const float* __restrict__ bq,
    const float* __restrict__ Wk, const float* __restrict__ bk,
    const float* __restrict__ Wv, const float* __restrict__ bv,
    const float* __restrict__ Wr,
    float* __restrict__ P, float* __restrict__ qb, float* __restrict__ kb,
    float* __restrict__ vb, float* __restrict__ WrT) {
  int bid = blockIdx.x;
  int t = threadIdx.x;
  __shared__ __align__(16) float As[16][HH];

  if (bid < PT_END) {
    // ---- P tables as tiled GEMM: 8 rows x 64 cols per block ----
    int tab = bid / PT_PER_TAB;
    int rem = bid - tab * PT_PER_TAB;
    int tile = rem / 3, yc = rem - tile * 3;
    int row0 = 256 + tile * 8;          // rows 256..767 only
    const float* pe = (tab == 0) ? pe_ss : (tab == 1) ? pe_se
                    : (tab == 2) ? pe_es : pe_ee;
    for (int idx = t; idx < 8 * 40; idx += 256) {
      int r = idx / 40, c4 = idx - r * 40;
      *(float4*)&As[r][c4 * 4] =
          *(const float4*)(pe + (size_t)(row0 + r) * HH + c4 * 4);
    }
    __syncthreads();
    int c = (t & 63) + yc * 64;
    int wv = t >> 6;
    if (c < HH) {
      float acc0, acc1;
      acc0 = acc1 = (tab == 0) ? b_fus[c] : 0.0f;
      const float* wp = W_fus + (size_t)tab * HH * HH + c;
      int r0 = wv * 2, r1 = wv * 2 + 1;
      #pragma unroll 2
      for (int k = 0; k < HH; k += 8) {
        float w[8];
        #pragma unroll
        for (int q = 0; q < 8; ++q) w[q] = wp[(size_t)(k + q) * HH];
        float4 a0 = *(const float4*)&As[r0][k];
        float4 a1 = *(const float4*)&As[r0][k + 4];
        float4 b0 = *(const float4*)&As[r1][k];
        float4 b1_ = *(const float4*)&As[r1][k + 4];
        acc0 = fmaf(a0.x, w[0], acc0); acc0 = fmaf(a0.y, w[1], acc0);
        acc0 = fmaf(a0.z, w[2], acc0); acc0 = fmaf(a0.w, w[3], acc0);
        acc0 = fmaf(a1.x, w[4], acc0); acc0 = fmaf(a1.y, w[5], acc0);
        acc0 = fmaf(a1.z, w[6], acc0); acc0 = fmaf(a1.w, w[7], acc0);
        acc1 = fmaf(b0.x, w[0], acc1); acc1 = fmaf(b0.y, w[1], acc1);
        acc1 = fmaf(b0.z, w[2], acc1); acc1 = fmaf(b0.w, w[3], acc1);
        acc1 = fmaf(b1_.x, w[4], acc1); acc1 = fmaf(b1_.y, w[5], acc1);
        acc1 = fmaf(b1_.z, w[6], acc1); acc1 = fmaf(b1_.w, w[7], acc1);
      }
      P[((size_t)tab * TBL + row0 + r0) * HH + c] = acc0;
      P[((size_t)tab * TBL + row0 + r1) * HH + c] = acc1;
    }
  } else if (bid < QKV_END) {
    // ---- fused Q/K/V projection: 16 tokens x 64 cols-of-480 ----
    int qbid = bid - PT_END;
    int bx = qbid & 63, by = qbid >> 6;
    int tok0 = bx * 16;
    {
      const float4* src = (const float4*)(inp + (size_t)tok0 * HH);
      float4* dst = (float4*)As;
      for (int idx = t; idx < 16 * HH / 4; idx += 256) dst[idx] = src[idx];
    }
    __syncthreads();
    int col = (t & 63) + by * 64;
    int wv = t >> 6;
    if (col < 480) {
      int mat = col / 160;
      int c = col - mat * 160;
      const float* W   = (mat == 0) ? Wq : (mat == 1) ? Wk : Wv;
      const float* bia = (mat == 0) ? bq : (mat == 1) ? bk : bv;
      float* O         = (mat == 0) ? qb : (mat == 1) ? kb : vb;
      float acc[4];
      float bb = bia[c];
      #pragma unroll
      for (int i = 0; i < 4; ++i) acc[i] = bb;
      const float* wp = W + c;
      #pragma unroll 2
      for (int k = 0; k < HH; k += 8) {
        float w[8];
        #pragma unroll
        for (int q = 0; q < 8; ++q) w[q] = wp[(size_t)(k + q) * HH];
        #pragma unroll
        for (int i = 0; i < 4; ++i) {
          const float4 a0 = *(const float4*)&As[wv * 4 + i][k];
          const float4 a1 = *(const float4*)&As[wv * 4 + i][k + 4];
          acc[i] = fmaf(a0.x, w[0], acc[i]);
          acc[i] = fmaf(a0.y, w[1], acc[i]);
          acc[i] = fmaf(a0.z, w[2], acc[i]);
          acc[i] = fmaf(a0.w, w[3], acc[i]);
          acc[i] = fmaf(a1.x, w[4], acc[i]);
          acc[i] = fmaf(a1.y, w[5], acc[i]);
          acc[i] = fmaf(a1.z, w[6], acc[i]);
          acc[i] = fmaf(a1.w, w[7], acc[i]);
        }
      }
      #pragma unroll
      for (int i = 0; i < 4; ++i)
        O[(size_t)(tok0 + wv * 4 + i) * HH + c] = acc[i];
    }
  } else {
    // ---- WrT[cp][cc] = Wr[cc][cp] ----
    int o = (bid - QKV_END) * 256 + t;
    int cp = o / HH, cc = o - cp * HH;
    WrT[o] = Wr[(size_t)cc * HH + cp];
  }
}

// ---------------------------------------------------------------------------
// Generic tiled GEMM: C[M,N] = op(A[M,KK] @ W[KK,N] + bias)
// ---------------------------------------------------------------------------
template<int TT, int KK, bool RELU>
__global__ __launch_bounds__(256) void k_gemm(
    const float* __restrict__ A, const float* __restrict__ W,
    const float* __restrict__ bias, float* __restrict__ C, int N) {
  const int TPW = TT / 4;
  int tok0 = blockIdx.x * TT;
  int t = threadIdx.x;
  __shared__ __align__(16) float As[TT][KK];
  {
    const float4* src = (const float4*)(A + (size_t)tok0 * KK);
    float4* dst = (float4*)As;
    for (int idx = t; idx < TT * KK / 4; idx += 256) dst[idx] = src[idx];
  }
  __syncthreads();
  int c = (t & 63) + blockIdx.y * 64;
  int wv = t >> 6;
  if (c < N) {
    float acc[TPW];
    float bb = bias ? bias[c] : 0.0f;
    #pragma unroll
    for (int i = 0; i < TPW; ++i) acc[i] = bb;
    const float* wp = W + c;
    #pragma unroll 2
    for (int k = 0; k < KK; k += 8) {
      float w[8];
      #pragma unroll
      for (int q = 0; q < 8; ++q) w[q] = wp[(size_t)(k + q) * N];
      #pragma unroll
      for (int i = 0; i < TPW; ++i) {
        const float4 a0 = *(const float4*)&As[wv * TPW + i][k];
        const float4 a1 = *(const float4*)&As[wv * TPW + i][k + 4];
        acc[i] = fmaf(a0.x, w[0], acc[i]);
        acc[i] = fmaf(a0.y, w[1], acc[i]);
        acc[i] = fmaf(a0.z, w[2], acc[i]);
        acc[i] = fmaf(a0.w, w[3], acc[i]);
        acc[i] = fmaf(a1.x, w[4], acc[i]);
        acc[i] = fmaf(a1.y, w[5], acc[i]);
        acc[i] = fmaf(a1.z, w[6], acc[i]);
        acc[i] = fmaf(a1.w, w[7], acc[i]);
      }
    }
    #pragma unroll
    for (int i = 0; i < TPW; ++i) {
      float v = RELU ? fmaxf(acc[i], 0.0f) : acc[i];
      C[(size_t)(tok0 + wv * TPW + i) * N + c] = v;
    }
  }
}

// ---------------------------------------------------------------------------
// LN1 + W1 + relu fused.
// ---------------------------------------------------------------------------
__global__ __launch_bounds__(256) void k_ffn1(
    const float* __restrict__ Y, const float* __restrict__ g1,
    const float* __restrict__ b1ln, const float* __restrict__ W1,
    const float* __restrict__ b1, float* __restrict__ Hb) {
  const int TT = 16;
  int tok0 = blockIdx.x * TT;
  int t = threadIdx.x;
  __shared__ __align__(16) float As[TT][HH];
  {
    const float4* src = (const float4*)(Y + (size_t)tok0 * HH);
    float4* dst = (float4*)As;
    for (int idx = t; idx < TT * HH / 4; idx += 256) dst[idx] = src[idx];
  }
  __syncthreads();
  {
    int row = t >> 4, l = t & 15;
    float s = 0.0f;
    #pragma unroll
    for (int c = l; c < HH; c += 16) s += As[row][c];
    #pragma unroll
    for (int m = 1; m < 16; m <<= 1) s += __shfl_xor(s, m);
    float mu = s * (1.0f / HH);
    float s2 = 0.0f;
    #pragma unroll
    for (int c = l; c < HH; c += 16) { float d = As[row][c] - mu; s2 = fmaf(d, d, s2); }
    #pragma unroll
    for (int m = 1; m < 16; m <<= 1) s2 += __shfl_xor(s2, m);
    float rstd = rsqrtf(s2 * (1.0f / HH) + 2.5e-6f);  // eps 1e-5 / 4
    #pragma unroll
    for (int c = l; c < HH; c += 16)
      As[row][c] = (As[row][c] - mu) * rstd * g1[c] + b1ln[c];
  }
  __syncthreads();
  int c = (t & 63) + blockIdx.y * 64;
  int wv = t >> 6;
  float acc[4];
  float bb = b1[c];
  #pragma unroll
  for (int i = 0; i < 4; ++i) acc[i] = bb;
  const float* wp = W1 + c;
  #pragma unroll 2
  for (int k = 0; k < HH; k += 8) {
    float w[8];
    #pragma unroll
    for (int q = 0; q < 8; ++q) w[q] = wp[(size_t)(k + q) * FF_];
    #pragma unroll
    for (int i = 0; i < 4; ++i) {
      const float4 a0 = *(const float4*)&As[wv * 4 + i][k];
      const float4 a1 = *(const float4*)&As[wv * 4 + i][k + 4];
      acc[i] = fmaf(a0.x, w[0], acc[i]);
      acc[i] = fmaf(a0.y, w[1], acc[i]);
      acc[i] = fmaf(a0.z, w[2], acc[i]);
      acc[i] = fmaf(a0.w, w[3], acc[i]);
      acc[i] = fmaf(a1.x, w[4], acc[i]);
      acc[i] = fmaf(a1.y, w[5], acc[i]);
      acc[i] = fmaf(a1.z, w[6], acc[i]);
      acc[i] = fmaf(a1.w, w[7], acc[i]);
    }
  }
  #pragma unroll
  for (int i = 0; i < 4; ++i)
    Hb[(size_t)(tok0 + wv * 4 + i) * FF_ + c] = fmaxf(acc[i], 0.0f);
}

// ---------------------------------------------------------------------------
// Fused attention, 512 threads (8 waves) per (b,i).  launch_bounds(512,4):
// VGPR cap 128 -> compiler uses ~60 (no spills, R7's (512,8) forced 32 and
// spilled 270 MB to scratch); at 60 VGPR the HW still fits 8 waves/SIMD.
// Wave w owns j in [w*32, w*32+32), 2 passes of 16.  Wave-uniform mask skip.
// ---------------------------------------------------------------------------
#define RSTR 164
#define SCS  257

__global__ __launch_bounds__(512, 4) void k_attn(
    const float* __restrict__ qb, const float* __restrict__ kb, const float* __restrict__ vb,
    const float* __restrict__ WrT, const float* __restrict__ P,
    const int* __restrict__ pos_s, const int* __restrict__ pos_e,
    const int* __restrict__ seq_len, const int* __restrict__ lex_num,
    const float* __restrict__ utab, const float* __restrict__ vtab,
    float* __restrict__ attn_out) {
  int blk = blockIdx.x;        // b*S + i
  int b = blk >> 8;
  int i = blk & 255;
  int t = threadIdx.x;
  __shared__ __align__(16) float qu[HH];
  __shared__ __align__(16) float qv_s[HH];
  __shared__ __align__(16) float g_s[NH_][RSTR];
  __shared__ __align__(16) float sc[NH_][SCS];
  __shared__ int ps_s[SS], pe_s[SS];

  if (t < HH) {
    float q = qb[(size_t)blk * HH + t];
    qu[t] = q + utab[t];
    qv_s[t] = q + vtab[t];
  }
  if (t < SS) {
    ps_s[t] = pos_s[b * SS + t];
    pe_s[t] = pos_e[b * SS + t];
  }
  __syncthreads();

  // g[h][cc] = sum_d qv[20h+d] * WrT[(20h+d)*160+cc]
  for (int p = t; p < NH_ * HH; p += 512) {
    int h = p / HH, cc = p - h * HH;
    const float* wp = WrT + (size_t)(h * HD_) * HH + cc;
    float acc = 0.0f;
    #pragma unroll
    for (int d = 0; d < HD_; ++d)
      acc = fmaf(qv_s[h * HD_ + d], wp[(size_t)d * HH], acc);
    g_s[h][cc] = acc;
  }
  __syncthreads();

  int w = t >> 6, lane = t & 63;
  int jj = lane >> 2, cg = lane & 3;
  int psi = ps_s[i], pei = pe_s[i];
  int limit = seq_len[b] + lex_num[0];
  const float scale = 0.22360679774997896f;  // 1/sqrt(20)

  const float4* P40 = (const float4*)P;
  const float4* P41 = P40 + (size_t)TBL * 40;
  const float4* P42 = P41 + (size_t)TBL * 40;
  const float4* P43 = P42 + (size_t)TBL * 40;
  const float4* kb4 = (const float4*)(kb + (size_t)b * SS * HH);

  #pragma unroll
  for (int pass = 0; pass < 2; ++pass) {
    int jbase = w * 32 + pass * 16;
    int j = jbase + jj;
    if (jbase >= limit) {            // wave-uniform: whole tile masked
      sc[2 * cg][j]     = -1.0e15f;
      sc[2 * cg + 1][j] = -1.0e15f;
      continue;
    }
    int psj = ps_s[j], pej = pe_s[j];
    int o0 = (psi - psj + MAXL) * 40 + cg;
    int o1 = (psi - pej + MAXL) * 40 + cg;
    int o2 = (pei - psj + MAXL) * 40 + cg;
    int o3 = (pei - pej + MAXL) * 40 + cg;
    float bd[NH_];
    #pragma unroll
    for (int h = 0; h < NH_; ++h) bd[h] = 0.0f;
    // immediate-consume gather: 4 loads -> relu -> 32 FMAs, per q
    #pragma unroll 2
    for (int q = 0; q < 10; ++q) {
      float4 a0 = P40[o0 + q * 4];
      float4 a1 = P41[o1 + q * 4];
      float4 a2 = P42[o2 + q * 4];
      float4 a3 = P43[o3 + q * 4];
      float rl0 = fmaxf(a0.x + a1.x + a2.x + a3.x, 0.0f);
      float rl1 = fmaxf(a0.y + a1.y + a2.y + a3.y, 0.0f);
      float rl2 = fmaxf(a0.z + a1.z + a2.z + a3.z, 0.0f);
      float rl3 = fmaxf(a0.w + a1.w + a2.w + a3.w, 0.0f);
      int c4 = (q * 4 + cg) * 4;
      #pragma unroll
      for (int h = 0; h < NH_; ++h) {
        float4 g4 = *(const float4*)&g_s[h][c4];
        bd[h] = fmaf(rl0, g4.x, bd[h]);
        bd[h] = fmaf(rl1, g4.y, bd[h]);
        bd[h] = fmaf(rl2, g4.z, bd[h]);
        bd[h] = fmaf(rl3, g4.w, bd[h]);
      }
    }
    // A_C for heads 2cg, 2cg+1 : c in [40cg, 40cg+40)
    float ac0 = 0.0f, ac1 = 0.0f;
    {
      int kbase = j * 40 + 10 * cg;
      #pragma unroll
      for (int m = 0; m < 10; ++m) {
        float4 kv = kb4[kbase + m];
        float4 q4 = *(const float4*)&qu[(10 * cg + m) * 4];
        if (m < 5) {
          ac0 = fmaf(q4.x, kv.x, ac0); ac0 = fmaf(q4.y, kv.y, ac0);
          ac0 = fmaf(q4.z, kv.z, ac0); ac0 = fmaf(q4.w, kv.w, ac0);
        } else {
          ac1 = fmaf(q4.x, kv.x, ac1); ac1 = fmaf(q4.y, kv.y, ac1);
          ac1 = fmaf(q4.z, kv.z, ac1); ac1 = fmaf(q4.w, kv.w, ac1);
        }
      }
    }
    #pragma unroll
    for (int h = 0; h < NH_; ++h) {
      bd[h] += __shfl_xor(bd[h], 1);
      bd[h] += __shfl_xor(bd[h], 2);
    }
    float s0, s1;
    if      (cg == 0) { s0 = bd[0]; s1 = bd[1]; }
    else if (cg == 1) { s0 = bd[2]; s1 = bd[3]; }
    else if (cg == 2) { s0 = bd[4]; s1 = bd[5]; }
    else              { s0 = bd[6]; s1 = bd[7]; }
    bool valid = (j < limit);
    sc[2 * cg][j]     = valid ? (s0 + ac0) * scale : -1.0e15f;
    sc[2 * cg + 1][j] = valid ? (s1 + ac1) * scale : -1.0e15f;
  }
  __syncthreads();

  // softmax: first 256 threads, 8 groups of 32 lanes, one head each
  if (t < 256) {
    int h = t >> 5, l = t & 31;
    float m = -3.0e38f;
    float e[8];
    #pragma unroll
    for (int ii = 0; ii < 8; ++ii) m = fmaxf(m, sc[h][l + ii * 32]);
    #pragma unroll
    for (int msk = 16; msk; msk >>= 1) m = fmaxf(m, __shfl_xor(m, msk));
    float s = 0.0f;
    #pragma unroll
    for (int ii = 0; ii < 8; ++ii) { e[ii] = __expf(sc[h][l + ii * 32] - m); s += e[ii]; }
    #pragma unroll
    for (int msk = 16; msk; msk >>= 1) s += __shfl_xor(s, msk);
    float inv = 1.0f / s;
    #pragma unroll
    for (int ii = 0; ii < 8; ++ii) sc[h][l + ii * 32] = e[ii] * inv;
  }
  __syncthreads();

  // PV: 2 threads per output column; each sums half the (clipped) j range.
  if (t < 2 * HH) {
    int c = t >> 1, half = t & 1;
    int h = c / HD_;
    int jstart = half * 128;
    int jend = min(limit, jstart + 128);
    float acc0 = 0.f, acc1 = 0.f;
    const float* vcol = vb + (size_t)b * SS * HH + c;
    for (int j2 = jstart; j2 + 1 < jend; j2 += 2) {
      acc0 = fmaf(sc[h][j2],     vcol[(size_t)j2 * HH],       acc0);
      acc1 = fmaf(sc[h][j2 + 1], vcol[(size_t)(j2 + 1) * HH], acc1);
    }
    if (((jend - jstart) & 1) && jend > jstart)
      acc0 = fmaf(sc[h][jend - 1], vcol[(size_t)(jend - 1) * HH], acc0);
    float acc = acc0 + acc1;
    acc += __shfl_xor(acc, 1);
    if (half == 0) attn_out[(size_t)blk * HH + c] = acc;
  }
}

// ---------------------------------------------------------------------------
// Final LayerNorm.  LN(y+y) == LN(y) with eps/4.
// ---------------------------------------------------------------------------
__global__ __launch_bounds__(256) void k_ln(
    const float* __restrict__ Y, const float* __restrict__ g,
    const float* __restrict__ bln, float* __restrict__ O) {
  int tok = blockIdx.x * 4 + (threadIdx.x >> 6);
  int l = threadIdx.x & 63;
  const float* y = Y + (size_t)tok * HH;
  float a = y[l];
  float bv = y[l + 64];
  bool has3 = l < (HH - 128);
  float cv = has3 ? y[l + 128] : 0.0f;
  float s = a + bv + cv;
  #pragma unroll
  for (int m = 32; m; m >>= 1) s += __shfl_xor(s, m);
  float mu = s * (1.0f / HH);
  float da = a - mu, db = bv - mu, dc = has3 ? (cv - mu) : 0.0f;
  float s2 = da * da + db * db + dc * dc;
  #pragma unroll
  for (int m = 32; m; m >>= 1) s2 += __shfl_xor(s2, m);
  float rstd = rsqrtf(s2 * (1.0f / HH) + 2.5e-6f);  // eps 1e-5 / 4
  float* o = O + (size_t)tok * HH;
  o[l]      = da * rstd * g[l] + bln[l];
  o[l + 64] = db * rstd * g[l + 64] + bln[l + 64];
  if (has3) o[l + 128] = dc * rstd * g[l + 128] + bln[l + 128];
}

// ---------------------------------------------------------------------------
extern "C" void kernel_launch(void* const* d_in, const int* in_sizes, int n_in,
                              void* d_out, int out_size, void* d_ws, size_t ws_size,
                              hipStream_t stream) {
  const float* inp    = (const float*)d_in[0];
  const int*   pos_s  = (const int*)d_in[1];
  const int*   pos_e  = (const int*)d_in[2];
  const int*   seq_ln = (const int*)d_in[3];
  const int*   lex_nm = (const int*)d_in[4];
  const float* pe_ss  = (const float*)d_in[5];
  const float* pe_se  = (const float*)d_in[6];
  const float* pe_es  = (const float*)d_in[7];
  const float* pe_ee  = (const float*)d_in[8];
  const float* W_fus  = (const float*)d_in[9];
  const float* b_fus  = (const float*)d_in[10];
  const float* Wq     = (const float*)d_in[11];
  const float* bq     = (const float*)d_in[12];
  const float* Wk     = (const float*)d_in[13];
  const float* bk     = (const float*)d_in[14];
  const float* Wv     = (const float*)d_in[15];
  const float* bv     = (const float*)d_in[16];
  const float* Wr     = (const float*)d_in[17];
  // d_in[18] = br : constant-over-j term, cancels in softmax
  const float* utab   = (const float*)d_in[19];
  const float* vtab   = (const float*)d_in[20];
  const float* W_fin  = (const float*)d_in[21];
  const float* b_fin  = (const float*)d_in[22];
  const float* ln1_g  = (const float*)d_in[23];
  const float* ln1_b  = (const float*)d_in[24];
  const float* W1     = (const float*)d_in[25];
  const float* b1     = (const float*)d_in[26];
  const float* W2     = (const float*)d_in[27];
  const float* b2     = (const float*)d_in[28];
  const float* ln2_g  = (const float*)d_in[29];
  const float* ln2_b  = (const float*)d_in[30];

  float* ws = (float*)d_ws;
  float* P        = ws;                        // 4*1025*160 = 656000
  float* qb       = P + 4 * TBL * HH;          // 163840 each
  float* kb       = qb + BB * SS * HH;
  float* vb       = kb + BB * SS * HH;
  float* WrT      = vb + BB * SS * HH;         // 25600
  float* attn_out = WrT + HH * HH;             // 163840
  float* ybuf     = attn_out + BB * SS * HH;   // 163840
  float* hbuf     = ybuf + BB * SS * HH;       // 655360
  float* y2       = hbuf + (size_t)BB * SS * FF_;  // 163840

  (void)in_sizes; (void)n_in; (void)out_size; (void)ws_size;

  const int M = BB * SS;  // 1024

  k_setup<<<WRT_END, 256, 0, stream>>>(pe_ss, pe_se, pe_es, pe_ee, W_fus, b_fus,
                                       inp, Wq, bq, Wk, bk, Wv, bv, Wr,
                                       P, qb, kb, vb, WrT);
  k_attn<<<M, 512, 0, stream>>>(qb, kb, vb, WrT, P, pos_s, pos_e, seq_ln, lex_nm,
                                utab, vtab, attn_out);
  k_gemm<4, HH, false><<<dim3(M / 4, 3), 256, 0, stream>>>(attn_out, W_fin, b_fin, ybuf, HH);
  k_ffn1<<<dim3(M / 16, 10), 256, 0, stream>>>(ybuf, ln1_g, ln1_b, W1, b1, hbuf);
  k_gemm<4, FF_, false><<<dim3(M / 4, 3), 256, 0, stream>>>(hbuf, W2, b2, y2, HH);
  k_ln<<<M / 4, 256, 0, stream>>>(y2, ln2_g, ln2_b, (float*)d_out);
}

// Round 9
// 115.084 us; speedup vs baseline: 1.3922x; 1.0584x over previous
//
#include <hip/hip_runtime.h>
#include <math.h>

// Problem constants
#define SS    256      // seq len
#define BB    4        // batch
#define HH    160      // hidden
#define NH_   8        // heads
#define HD_   20       // head dim
#define TBL   1025     // 2*MAXLEN+1
#define MAXL  512
#define FF_   640

// setup-kernel block ranges.  P rows actually used are [257,767].
#define PT_TILES 64                    // 512 rows / 8
#define PT_PER_TAB (PT_TILES * 3)      // 192
#define PT_END (4 * PT_PER_TAB)        // 768
#define QKV_END (PT_END + 512)         // + (1024/16) x 8
#define WRT_END (QKV_END + 100)        // + 25600/256

// ---------------------------------------------------------------------------
// Mega setup kernel: [0,768) ptab-as-GEMM (rows 256..767); [768,1280) QKV;
// [1280,1380) WrT.  All branches block-uniform.
// ---------------------------------------------------------------------------
__global__ __launch_bounds__(256) void k_setup(
    const float* __restrict__ pe_ss, const float* __restrict__ pe_se,
    const float* __restrict__ pe_es, const float* __restrict__ pe_ee,
    const float* __restrict__ W_fus, const float* __restrict__ b_fus,
    const float* __restrict__ inp,
    const float* __restrict__ Wq, const float* __restrict__ bq,
    const float* __restrict__ Wk, const float* __restrict__ bk,
    const float* __restrict__ Wv, const float* __restrict__ bv,
    const float* __restrict__ Wr,
    float* __restrict__ P, float* __restrict__ qb, float* __restrict__ kb,
    float* __restrict__ vb, float* __restrict__ WrT) {
  int bid = blockIdx.x;
  int t = threadIdx.x;
  __shared__ __align__(16) float As[16][HH];

  if (bid < PT_END) {
    int tab = bid / PT_PER_TAB;
    int rem = bid - tab * PT_PER_TAB;
    int tile = rem / 3, yc = rem - tile * 3;
    int row0 = 256 + tile * 8;          // rows 256..767 only
    const float* pe = (tab == 0) ? pe_ss : (tab == 1) ? pe_se
                    : (tab == 2) ? pe_es : pe_ee;
    for (int idx = t; idx < 8 * 40; idx += 256) {
      int r = idx / 40, c4 = idx - r * 40;
      *(float4*)&As[r][c4 * 4] =
          *(const float4*)(pe + (size_t)(row0 + r) * HH + c4 * 4);
    }
    __syncthreads();
    int c = (t & 63) + yc * 64;
    int wv = t >> 6;
    if (c < HH) {
      float acc0, acc1;
      acc0 = acc1 = (tab == 0) ? b_fus[c] : 0.0f;
      const float* wp = W_fus + (size_t)tab * HH * HH + c;
      int r0 = wv * 2, r1 = wv * 2 + 1;
      #pragma unroll 2
      for (int k = 0; k < HH; k += 8) {
        float w[8];
        #pragma unroll
        for (int q = 0; q < 8; ++q) w[q] = wp[(size_t)(k + q) * HH];
        float4 a0 = *(const float4*)&As[r0][k];
        float4 a1 = *(const float4*)&As[r0][k + 4];
        float4 b0 = *(const float4*)&As[r1][k];
        float4 b1_ = *(const float4*)&As[r1][k + 4];
        acc0 = fmaf(a0.x, w[0], acc0); acc0 = fmaf(a0.y, w[1], acc0);
        acc0 = fmaf(a0.z, w[2], acc0); acc0 = fmaf(a0.w, w[3], acc0);
        acc0 = fmaf(a1.x, w[4], acc0); acc0 = fmaf(a1.y, w[5], acc0);
        acc0 = fmaf(a1.z, w[6], acc0); acc0 = fmaf(a1.w, w[7], acc0);
        acc1 = fmaf(b0.x, w[0], acc1); acc1 = fmaf(b0.y, w[1], acc1);
        acc1 = fmaf(b0.z, w[2], acc1); acc1 = fmaf(b0.w, w[3], acc1);
        acc1 = fmaf(b1_.x, w[4], acc1); acc1 = fmaf(b1_.y, w[5], acc1);
        acc1 = fmaf(b1_.z, w[6], acc1); acc1 = fmaf(b1_.w, w[7], acc1);
      }
      P[((size_t)tab * TBL + row0 + r0) * HH + c] = acc0;
      P[((size_t)tab * TBL + row0 + r1) * HH + c] = acc1;
    }
  } else if (bid < QKV_END) {
    int qbid = bid - PT_END;
    int bx = qbid & 63, by = qbid >> 6;
    int tok0 = bx * 16;
    {
      const float4* src = (const float4*)(inp + (size_t)tok0 * HH);
      float4* dst = (float4*)As;
      for (int idx = t; idx < 16 * HH / 4; idx += 256) dst[idx] = src[idx];
    }
    __syncthreads();
    int col = (t & 63) + by * 64;
    int wv = t >> 6;
    if (col < 480) {
      int mat = col / 160;
      int c = col - mat * 160;
      const float* W   = (mat == 0) ? Wq : (mat == 1) ? Wk : Wv;
      const float* bia = (mat == 0) ? bq : (mat == 1) ? bk : bv;
      float* O         = (mat == 0) ? qb : (mat == 1) ? kb : vb;
      float acc[4];
      float bb = bia[c];
      #pragma unroll
      for (int i = 0; i < 4; ++i) acc[i] = bb;
      const float* wp = W + c;
      #pragma unroll 2
      for (int k = 0; k < HH; k += 8) {
        float w[8];
        #pragma unroll
        for (int q = 0; q < 8; ++q) w[q] = wp[(size_t)(k + q) * HH];
        #pragma unroll
        for (int i = 0; i < 4; ++i) {
          const float4 a0 = *(const float4*)&As[wv * 4 + i][k];
          const float4 a1 = *(const float4*)&As[wv * 4 + i][k + 4];
          acc[i] = fmaf(a0.x, w[0], acc[i]);
          acc[i] = fmaf(a0.y, w[1], acc[i]);
          acc[i] = fmaf(a0.z, w[2], acc[i]);
          acc[i] = fmaf(a0.w, w[3], acc[i]);
          acc[i] = fmaf(a1.x, w[4], acc[i]);
          acc[i] = fmaf(a1.y, w[5], acc[i]);
          acc[i] = fmaf(a1.z, w[6], acc[i]);
          acc[i] = fmaf(a1.w, w[7], acc[i]);
        }
      }
      #pragma unroll
      for (int i = 0; i < 4; ++i)
        O[(size_t)(tok0 + wv * 4 + i) * HH + c] = acc[i];
    }
  } else {
    int o = (bid - QKV_END) * 256 + t;
    int cp = o / HH, cc = o - cp * HH;
    WrT[o] = Wr[(size_t)cc * HH + cp];
  }
}

// ---------------------------------------------------------------------------
// Generic tiled GEMM: C[M,N] = op(A[M,KK] @ W[KK,N] + bias)
// ---------------------------------------------------------------------------
template<int TT, int KK, bool RELU>
__global__ __launch_bounds__(256) void k_gemm(
    const float* __restrict__ A, const float* __restrict__ W,
    const float* __restrict__ bias, float* __restrict__ C, int N) {
  const int TPW = TT / 4;
  int tok0 = blockIdx.x * TT;
  int t = threadIdx.x;
  __shared__ __align__(16) float As[TT][KK];
  {
    const float4* src = (const float4*)(A + (size_t)tok0 * KK);
    float4* dst = (float4*)As;
    for (int idx = t; idx < TT * KK / 4; idx += 256) dst[idx] = src[idx];
  }
  __syncthreads();
  int c = (t & 63) + blockIdx.y * 64;
  int wv = t >> 6;
  if (c < N) {
    float acc[TPW];
    float bb = bias ? bias[c] : 0.0f;
    #pragma unroll
    for (int i = 0; i < TPW; ++i) acc[i] = bb;
    const float* wp = W + c;
    #pragma unroll 2
    for (int k = 0; k < KK; k += 8) {
      float w[8];
      #pragma unroll
      for (int q = 0; q < 8; ++q) w[q] = wp[(size_t)(k + q) * N];
      #pragma unroll
      for (int i = 0; i < TPW; ++i) {
        const float4 a0 = *(const float4*)&As[wv * TPW + i][k];
        const float4 a1 = *(const float4*)&As[wv * TPW + i][k + 4];
        acc[i] = fmaf(a0.x, w[0], acc[i]);
        acc[i] = fmaf(a0.y, w[1], acc[i]);
        acc[i] = fmaf(a0.z, w[2], acc[i]);
        acc[i] = fmaf(a0.w, w[3], acc[i]);
        acc[i] = fmaf(a1.x, w[4], acc[i]);
        acc[i] = fmaf(a1.y, w[5], acc[i]);
        acc[i] = fmaf(a1.z, w[6], acc[i]);
        acc[i] = fmaf(a1.w, w[7], acc[i]);
      }
    }
    #pragma unroll
    for (int i = 0; i < TPW; ++i) {
      float v = RELU ? fmaxf(acc[i], 0.0f) : acc[i];
      C[(size_t)(tok0 + wv * TPW + i) * N + c] = v;
    }
  }
}

// ---------------------------------------------------------------------------
// LN1 + W1 + relu fused.
// ---------------------------------------------------------------------------
__global__ __launch_bounds__(256) void k_ffn1(
    const float* __restrict__ Y, const float* __restrict__ g1,
    const float* __restrict__ b1ln, const float* __restrict__ W1,
    const float* __restrict__ b1, float* __restrict__ Hb) {
  const int TT = 16;
  int tok0 = blockIdx.x * TT;
  int t = threadIdx.x;
  __shared__ __align__(16) float As[TT][HH];
  {
    const float4* src = (const float4*)(Y + (size_t)tok0 * HH);
    float4* dst = (float4*)As;
    for (int idx = t; idx < TT * HH / 4; idx += 256) dst[idx] = src[idx];
  }
  __syncthreads();
  {
    int row = t >> 4, l = t & 15;
    float s = 0.0f;
    #pragma unroll
    for (int c = l; c < HH; c += 16) s += As[row][c];
    #pragma unroll
    for (int m = 1; m < 16; m <<= 1) s += __shfl_xor(s, m);
    float mu = s * (1.0f / HH);
    float s2 = 0.0f;
    #pragma unroll
    for (int c = l; c < HH; c += 16) { float d = As[row][c] - mu; s2 = fmaf(d, d, s2); }
    #pragma unroll
    for (int m = 1; m < 16; m <<= 1) s2 += __shfl_xor(s2, m);
    float rstd = rsqrtf(s2 * (1.0f / HH) + 2.5e-6f);  // eps 1e-5 / 4
    #pragma unroll
    for (int c = l; c < HH; c += 16)
      As[row][c] = (As[row][c] - mu) * rstd * g1[c] + b1ln[c];
  }
  __syncthreads();
  int c = (t & 63) + blockIdx.y * 64;
  int wv = t >> 6;
  float acc[4];
  float bb = b1[c];
  #pragma unroll
  for (int i = 0; i < 4; ++i) acc[i] = bb;
  const float* wp = W1 + c;
  #pragma unroll 2
  for (int k = 0; k < HH; k += 8) {
    float w[8];
    #pragma unroll
    for (int q = 0; q < 8; ++q) w[q] = wp[(size_t)(k + q) * FF_];
    #pragma unroll
    for (int i = 0; i < 4; ++i) {
      const float4 a0 = *(const float4*)&As[wv * 4 + i][k];
      const float4 a1 = *(const float4*)&As[wv * 4 + i][k + 4];
      acc[i] = fmaf(a0.x, w[0], acc[i]);
      acc[i] = fmaf(a0.y, w[1], acc[i]);
      acc[i] = fmaf(a0.z, w[2], acc[i]);
      acc[i] = fmaf(a0.w, w[3], acc[i]);
      acc[i] = fmaf(a1.x, w[4], acc[i]);
      acc[i] = fmaf(a1.y, w[5], acc[i]);
      acc[i] = fmaf(a1.z, w[6], acc[i]);
      acc[i] = fmaf(a1.w, w[7], acc[i]);
    }
  }
  #pragma unroll
  for (int i = 0; i < 4; ++i)
    Hb[(size_t)(tok0 + wv * 4 + i) * FF_ + c] = fmaxf(acc[i], 0.0f);
}

// ---------------------------------------------------------------------------
// Score kernel: grid (1024*2), 256 threads (4 waves).  Block = (b,i) x j-half
// (128 j's).  Computes B_D via coalesced immediate-consume P gather + A_C,
// writes raw scores (unscaled mask handled downstream) to global.
// Wave w handles tiles {w, 7-w} of 8 (16 j each) -> masked tiles balanced.
// Fully-masked halves return immediately; k_smpv applies the j>=limit mask.
// ---------------------------------------------------------------------------
#define RSTR 164
#define SCP  132   // sc_s row stride (528B, 16B-aligned)

__global__ __launch_bounds__(256, 4) void k_score(
    const float* __restrict__ qb, const float* __restrict__ kb,
    const float* __restrict__ WrT, const float* __restrict__ P,
    const int* __restrict__ pos_s, const int* __restrict__ pos_e,
    const int* __restrict__ seq_len, const int* __restrict__ lex_num,
    const float* __restrict__ utab, const float* __restrict__ vtab,
    float* __restrict__ scores) {
  int bid = blockIdx.x;
  int blk = bid >> 1;          // b*S + i
  int half = bid & 1;
  int b = blk >> 8;
  int i = blk & 255;
  int t = threadIdx.x;
  int limit = seq_len[b] + lex_num[0];
  if (half * 128 >= limit) return;   // whole half masked (uniform)

  __shared__ __align__(16) float qu[HH];
  __shared__ __align__(16) float qv_s[HH];
  __shared__ __align__(16) float g_s[NH_][RSTR];
  __shared__ __align__(16) float sc_s[NH_][SCP];
  __shared__ int ps_s[SS], pe_s[SS];

  if (t < HH) {
    float q = qb[(size_t)blk * HH + t];
    qu[t] = q + utab[t];
    qv_s[t] = q + vtab[t];
  }
  ps_s[t] = pos_s[b * SS + t];
  pe_s[t] = pos_e[b * SS + t];
  __syncthreads();

  // g[h][cc] = sum_d qv[20h+d] * WrT[(20h+d)*160+cc]  (1280 outputs, 5/thread)
  #pragma unroll
  for (int r = 0; r < 5; ++r) {
    int p = r * 256 + t;
    int h = p / HH, cc = p - h * HH;
    const float* wp = WrT + (size_t)(h * HD_) * HH + cc;
    float acc = 0.0f;
    #pragma unroll
    for (int d = 0; d < HD_; ++d)
      acc = fmaf(qv_s[h * HD_ + d], wp[(size_t)d * HH], acc);
    g_s[h][cc] = acc;
  }
  __syncthreads();

  int w = t >> 6, lane = t & 63;
  int jj = lane >> 2, cg = lane & 3;
  int psi = ps_s[i], pei = pe_s[i];
  const float scale = 0.22360679774997896f;  // 1/sqrt(20)

  const float4* P40 = (const float4*)P;
  const float4* P41 = P40 + (size_t)TBL * 40;
  const float4* P42 = P41 + (size_t)TBL * 40;
  const float4* P43 = P42 + (size_t)TBL * 40;
  const float4* kb4 = (const float4*)(kb + (size_t)b * SS * HH);

  #pragma unroll
  for (int pass = 0; pass < 2; ++pass) {
    int tau = (pass == 0) ? w : 7 - w;
    int jl = tau * 16 + jj;          // 0..127
    int j = half * 128 + jl;
    if (half * 128 + tau * 16 >= limit) continue;   // tile fully masked
    int psj = ps_s[j], pej = pe_s[j];
    int o0 = (psi - psj + MAXL) * 40 + cg;
    int o1 = (psi - pej + MAXL) * 40 + cg;
    int o2 = (pei - psj + MAXL) * 40 + cg;
    int o3 = (pei - pej + MAXL) * 40 + cg;
    float bd[NH_];
    #pragma unroll
    for (int h = 0; h < NH_; ++h) bd[h] = 0.0f;
    // immediate-consume gather: 4 loads -> relu -> 32 FMAs, per q
    #pragma unroll 2
    for (int q = 0; q < 10; ++q) {
      float4 a0 = P40[o0 + q * 4];
      float4 a1 = P41[o1 + q * 4];
      float4 a2 = P42[o2 + q * 4];
      float4 a3 = P43[o3 + q * 4];
      float rl0 = fmaxf(a0.x + a1.x + a2.x + a3.x, 0.0f);
      float rl1 = fmaxf(a0.y + a1.y + a2.y + a3.y, 0.0f);
      float rl2 = fmaxf(a0.z + a1.z + a2.z + a3.z, 0.0f);
      float rl3 = fmaxf(a0.w + a1.w + a2.w + a3.w, 0.0f);
      int c4 = (q * 4 + cg) * 4;
      #pragma unroll
      for (int h = 0; h < NH_; ++h) {
        float4 g4 = *(const float4*)&g_s[h][c4];
        bd[h] = fmaf(rl0, g4.x, bd[h]);
        bd[h] = fmaf(rl1, g4.y, bd[h]);
        bd[h] = fmaf(rl2, g4.z, bd[h]);
        bd[h] = fmaf(rl3, g4.w, bd[h]);
      }
    }
    // A_C for heads 2cg, 2cg+1 : c in [40cg, 40cg+40)
    float ac0 = 0.0f, ac1 = 0.0f;
    {
      int kbase = j * 40 + 10 * cg;
      #pragma unroll
      for (int m = 0; m < 10; ++m) {
        float4 kv = kb4[kbase + m];
        float4 q4 = *(const float4*)&qu[(10 * cg + m) * 4];
        if (m < 5) {
          ac0 = fmaf(q4.x, kv.x, ac0); ac0 = fmaf(q4.y, kv.y, ac0);
          ac0 = fmaf(q4.z, kv.z, ac0); ac0 = fmaf(q4.w, kv.w, ac0);
        } else {
          ac1 = fmaf(q4.x, kv.x, ac1); ac1 = fmaf(q4.y, kv.y, ac1);
          ac1 = fmaf(q4.z, kv.z, ac1); ac1 = fmaf(q4.w, kv.w, ac1);
        }
      }
    }
    // reduce bd over the 4 cg lanes
    #pragma unroll
    for (int h = 0; h < NH_; ++h) {
      bd[h] += __shfl_xor(bd[h], 1);
      bd[h] += __shfl_xor(bd[h], 2);
    }
    float s0, s1;
    if      (cg == 0) { s0 = bd[0]; s1 = bd[1]; }
    else if (cg == 1) { s0 = bd[2]; s1 = bd[3]; }
    else if (cg == 2) { s0 = bd[4]; s1 = bd[5]; }
    else              { s0 = bd[6]; s1 = bd[7]; }
    sc_s[2 * cg][jl]     = (s0 + ac0) * scale;
    sc_s[2 * cg + 1][jl] = (s1 + ac1) * scale;
  }
  __syncthreads();

  // coalesced writeout: 8 rows x 32 float4
  {
    int row = t >> 5, c4 = t & 31;
    float4 v = *(const float4*)&sc_s[row][c4 * 4];
    *(float4*)&scores[((size_t)blk * NH_ + row) * SS + half * 128 + c4 * 4] = v;
  }
}

// ---------------------------------------------------------------------------
// Softmax + PV kernel: grid 1024, 256 threads.  Masks j>=limit (so k_score
// never needs to write masked scores), softmax per head, PV clipped to limit.
// ---------------------------------------------------------------------------
#define SCS 260   // 1040B row stride, 16B aligned

__global__ __launch_bounds__(256, 4) void k_smpv(
    const float* __restrict__ scores, const float* __restrict__ vb,
    const int* __restrict__ seq_len, const int* __restrict__ lex_num,
    float* __restrict__ attn_out) {
  int blk = blockIdx.x;
  int b = blk >> 8;
  int t = threadIdx.x;
  __shared__ __align__(16) float sc[NH_][SCS];
  int limit = seq_len[b] + lex_num[0];

  const float4* src = (const float4*)(scores + (size_t)blk * NH_ * SS);
  #pragma unroll
  for (int r = 0; r < 2; ++r) {
    int idx = r * 256 + t;           // 0..511 = 8 rows x 64 float4
    int row = idx >> 6, c4 = idx & 63;
    float4 v = src[idx];
    int j0 = c4 * 4;
    v.x = (j0 + 0 < limit) ? v.x : -1.0e15f;
    v.y = (j0 + 1 < limit) ? v.y : -1.0e15f;
    v.z = (j0 + 2 < limit) ? v.z : -1.0e15f;
    v.w = (j0 + 3 < limit) ? v.w : -1.0e15f;
    *(float4*)&sc[row][j0] = v;
  }
  __syncthreads();

  // softmax: 8 groups of 32 lanes, one head each
  {
    int h = t >> 5, l = t & 31;
    float m = -3.0e38f;
    float e[8];
    #pragma unroll
    for (int ii = 0; ii < 8; ++ii) m = fmaxf(m, sc[h][l + ii * 32]);
    #pragma unroll
    for (int msk = 16; msk; msk >>= 1) m = fmaxf(m, __shfl_xor(m, msk));
    float s = 0.0f;
    #pragma unroll
    for (int ii = 0; ii < 8; ++ii) { e[ii] = __expf(sc[h][l + ii * 32] - m); s += e[ii]; }
    #pragma unroll
    for (int msk = 16; msk; msk >>= 1) s += __shfl_xor(s, msk);
    float inv = 1.0f / s;
    #pragma unroll
    for (int ii = 0; ii < 8; ++ii) sc[h][l + ii * 32] = e[ii] * inv;
  }
  __syncthreads();

  // PV: thread c<160 computes out[c]; loop clipped to limit (sc=0 in pad).
  if (t < HH) {
    int h = t / HD_;
    int lim4 = (limit + 3) & ~3;
    float acc0 = 0.f, acc1 = 0.f, acc2 = 0.f, acc3 = 0.f;
    const float* vcol = vb + (size_t)b * SS * HH + t;
    for (int j2 = 0; j2 < lim4; j2 += 4) {
      float4 p4 = *(const float4*)&sc[h][j2];
      acc0 = fmaf(p4.x, vcol[(size_t)(j2 + 0) * HH], acc0);
      acc1 = fmaf(p4.y, vcol[(size_t)(j2 + 1) * HH], acc1);
      acc2 = fmaf(p4.z, vcol[(size_t)(j2 + 2) * HH], acc2);
      acc3 = fmaf(p4.w, vcol[(size_t)(j2 + 3) * HH], acc3);
    }
    attn_out[(size_t)blk * HH + t] = (acc0 + acc1) + (acc2 + acc3);
  }
}

// ---------------------------------------------------------------------------
// Final LayerNorm.  LN(y+y) == LN(y) with eps/4.
// ---------------------------------------------------------------------------
__global__ __launch_bounds__(256) void k_ln(
    const float* __restrict__ Y, const float* __restrict__ g,
    const float* __restrict__ bln, float* __restrict__ O) {
  int tok = blockIdx.x * 4 + (threadIdx.x >> 6);
  int l = threadIdx.x & 63;
  const float* y = Y + (size_t)tok * HH;
  float a = y[l];
  float bv = y[l + 64];
  bool has3 = l < (HH - 128);
  float cv = has3 ? y[l + 128] : 0.0f;
  float s = a + bv + cv;
  #pragma unroll
  for (int m = 32; m; m >>= 1) s += __shfl_xor(s, m);
  float mu = s * (1.0f / HH);
  float da = a - mu, db = bv - mu, dc = has3 ? (cv - mu) : 0.0f;
  float s2 = da * da + db * db + dc * dc;
  #pragma unroll
  for (int m = 32; m; m >>= 1) s2 += __shfl_xor(s2, m);
  float rstd = rsqrtf(s2 * (1.0f / HH) + 2.5e-6f);  // eps 1e-5 / 4
  float* o = O + (size_t)tok * HH;
  o[l]      = da * rstd * g[l] + bln[l];
  o[l + 64] = db * rstd * g[l + 64] + bln[l + 64];
  if (has3) o[l + 128] = dc * rstd * g[l + 128] + bln[l + 128];
}

// ---------------------------------------------------------------------------
extern "C" void kernel_launch(void* const* d_in, const int* in_sizes, int n_in,
                              void* d_out, int out_size, void* d_ws, size_t ws_size,
                              hipStream_t stream) {
  const float* inp    = (const float*)d_in[0];
  const int*   pos_s  = (const int*)d_in[1];
  const int*   pos_e  = (const int*)d_in[2];
  const int*   seq_ln = (const int*)d_in[3];
  const int*   lex_nm = (const int*)d_in[4];
  const float* pe_ss  = (const float*)d_in[5];
  const float* pe_se  = (const float*)d_in[6];
  const float* pe_es  = (const float*)d_in[7];
  const float* pe_ee  = (const float*)d_in[8];
  const float* W_fus  = (const float*)d_in[9];
  const float* b_fus  = (const float*)d_in[10];
  const float* Wq     = (const float*)d_in[11];
  const float* bq     = (const float*)d_in[12];
  const float* Wk     = (const float*)d_in[13];
  const float* bk     = (const float*)d_in[14];
  const float* Wv     = (const float*)d_in[15];
  const float* bv     = (const float*)d_in[16];
  const float* Wr     = (const float*)d_in[17];
  // d_in[18] = br : constant-over-j term, cancels in softmax
  const float* utab   = (const float*)d_in[19];
  const float* vtab   = (const float*)d_in[20];
  const float* W_fin  = (const float*)d_in[21];
  const float* b_fin  = (const float*)d_in[22];
  const float* ln1_g  = (const float*)d_in[23];
  const float* ln1_b  = (const float*)d_in[24];
  const float* W1     = (const float*)d_in[25];
  const float* b1     = (const float*)d_in[26];
  const float* W2     = (const float*)d_in[27];
  const float* b2     = (const float*)d_in[28];
  const float* ln2_g  = (const float*)d_in[29];
  const float* ln2_b  = (const float*)d_in[30];

  float* ws = (float*)d_ws;
  float* P        = ws;                        // 656000
  float* qb       = P + 4 * TBL * HH;          // 163840 each
  float* kb       = qb + BB * SS * HH;
  float* vb       = kb + BB * SS * HH;
  float* WrT      = vb + BB * SS * HH;         // 25600
  float* attn_out = WrT + HH * HH;             // 163840
  float* scores   = attn_out + BB * SS * HH;   // 2097152 (1024*8*256)
  // scores is dead after k_smpv; alias the FFN buffers over it:
  float* ybuf     = scores;                    // 163840
  float* hbuf     = scores + 163840;           // 655360
  float* y2       = scores + 819200;           // 163840 (total 983040 < 2097152)

  (void)in_sizes; (void)n_in; (void)out_size; (void)ws_size;

  const int M = BB * SS;  // 1024

  k_setup<<<WRT_END, 256, 0, stream>>>(pe_ss, pe_se, pe_es, pe_ee, W_fus, b_fus,
                                       inp, Wq, bq, Wk, bk, Wv, bv, Wr,
                                       P, qb, kb, vb, WrT);
  k_score<<<2 * M, 256, 0, stream>>>(qb, kb, WrT, P, pos_s, pos_e, seq_ln, lex_nm,
                                     utab, vtab, scores);
  k_smpv<<<M, 256, 0, stream>>>(scores, vb, seq_ln, lex_nm, attn_out);
  k_gemm<4, HH, false><<<dim3(M / 4, 3), 256, 0, stream>>>(attn_out, W_fin, b_fin, ybuf, HH);
  k_ffn1<<<dim3(M / 16, 10), 256, 0, stream>>>(ybuf, ln1_g, ln1_b, W1, b1, hbuf);
  k_gemm<4, FF_, false><<<dim3(M / 4, 3), 256, 0, stream>>>(hbuf, W2, b2, y2, HH);
  k_ln<<<M / 4, 256, 0, stream>>>(y2, ln2_g, ln2_b, (float*)d_out);
}

// Round 10
// 112.136 us; speedup vs baseline: 1.4288x; 1.0263x over previous
//
#include <hip/hip_runtime.h>
#include <hip/hip_bf16.h>
#include <math.h>

// Problem constants
#define SS    256      // seq len
#define BB    4        // batch
#define HH    160      // hidden
#define NH_   8        // heads
#define HD_   20       // head dim
#define TBL   1025     // 2*MAXLEN+1
#define MAXL  512
#define FF_   640
#define PROWS 512      // live P rows: diff+256 in [1,511]

// setup-kernel block ranges
#define PT_TILES 64                    // 512 rows / 8
#define PT_PER_TAB (PT_TILES * 3)      // 192
#define PT_END (4 * PT_PER_TAB)        // 768
#define QKV_END (PT_END + 512)         // + (1024/16) x 8
#define WRT_END (QKV_END + 100)        // + 25600/256

__device__ __forceinline__ float blo(unsigned x) {
  return __uint_as_float(x << 16);
}
__device__ __forceinline__ float bhi(unsigned x) {
  return __uint_as_float(x & 0xffff0000u);
}

// ---------------------------------------------------------------------------
// Mega setup kernel: [0,768) ptab-as-GEMM -> bf16 P (rows 256..767 stored
// compactly as rloc=row-256 in [0,512)); [768,1280) QKV; [1280,1380) WrT.
// ---------------------------------------------------------------------------
__global__ __launch_bounds__(256) void k_setup(
    const float* __restrict__ pe_ss, const float* __restrict__ pe_se,
    const float* __restrict__ pe_es, const float* __restrict__ pe_ee,
    const float* __restrict__ W_fus, const float* __restrict__ b_fus,
    const float* __restrict__ inp,
    const float* __restrict__ Wq, const float* __restrict__ bq,
    const float* __restrict__ Wk, const float* __restrict__ bk,
    const float* __restrict__ Wv, const float* __restrict__ bv,
    const float* __restrict__ Wr,
    __hip_bfloat16* __restrict__ Pbf, float* __restrict__ qb,
    float* __restrict__ kb, float* __restrict__ vb, float* __restrict__ WrT) {
  int bid = blockIdx.x;
  int t = threadIdx.x;
  __shared__ __align__(16) float As[16][HH];

  if (bid < PT_END) {
    int tab = bid / PT_PER_TAB;
    int rem = bid - tab * PT_PER_TAB;
    int tile = rem / 3, yc = rem - tile * 3;
    int row0 = 256 + tile * 8;          // original rows 256..767
    const float* pe = (tab == 0) ? pe_ss : (tab == 1) ? pe_se
                    : (tab == 2) ? pe_es : pe_ee;
    for (int idx = t; idx < 8 * 40; idx += 256) {
      int r = idx / 40, c4 = idx - r * 40;
      *(float4*)&As[r][c4 * 4] =
          *(const float4*)(pe + (size_t)(row0 + r) * HH + c4 * 4);
    }
    __syncthreads();
    int c = (t & 63) + yc * 64;
    int wv = t >> 6;
    if (c < HH) {
      float acc0, acc1;
      acc0 = acc1 = (tab == 0) ? b_fus[c] : 0.0f;
      const float* wp = W_fus + (size_t)tab * HH * HH + c;
      int r0 = wv * 2, r1 = wv * 2 + 1;
      #pragma unroll 2
      for (int k = 0; k < HH; k += 8) {
        float w[8];
        #pragma unroll
        for (int q = 0; q < 8; ++q) w[q] = wp[(size_t)(k + q) * HH];
        float4 a0 = *(const float4*)&As[r0][k];
        float4 a1 = *(const float4*)&As[r0][k + 4];
        float4 b0 = *(const float4*)&As[r1][k];
        float4 b1_ = *(const float4*)&As[r1][k + 4];
        acc0 = fmaf(a0.x, w[0], acc0); acc0 = fmaf(a0.y, w[1], acc0);
        acc0 = fmaf(a0.z, w[2], acc0); acc0 = fmaf(a0.w, w[3], acc0);
        acc0 = fmaf(a1.x, w[4], acc0); acc0 = fmaf(a1.y, w[5], acc0);
        acc0 = fmaf(a1.z, w[6], acc0); acc0 = fmaf(a1.w, w[7], acc0);
        acc1 = fmaf(b0.x, w[0], acc1); acc1 = fmaf(b0.y, w[1], acc1);
        acc1 = fmaf(b0.z, w[2], acc1); acc1 = fmaf(b0.w, w[3], acc1);
        acc1 = fmaf(b1_.x, w[4], acc1); acc1 = fmaf(b1_.y, w[5], acc1);
        acc1 = fmaf(b1_.z, w[6], acc1); acc1 = fmaf(b1_.w, w[7], acc1);
      }
      int rloc = tile * 8;
      Pbf[((size_t)tab * PROWS + rloc + r0) * HH + c] = __float2bfloat16(acc0);
      Pbf[((size_t)tab * PROWS + rloc + r1) * HH + c] = __float2bfloat16(acc1);
    }
  } else if (bid < QKV_END) {
    int qbid = bid - PT_END;
    int bx = qbid & 63, by = qbid >> 6;
    int tok0 = bx * 16;
    {
      const float4* src = (const float4*)(inp + (size_t)tok0 * HH);
      float4* dst = (float4*)As;
      for (int idx = t; idx < 16 * HH / 4; idx += 256) dst[idx] = src[idx];
    }
    __syncthreads();
    int col = (t & 63) + by * 64;
    int wv = t >> 6;
    if (col < 480) {
      int mat = col / 160;
      int c = col - mat * 160;
      const float* W   = (mat == 0) ? Wq : (mat == 1) ? Wk : Wv;
      const float* bia = (mat == 0) ? bq : (mat == 1) ? bk : bv;
      float* O         = (mat == 0) ? qb : (mat == 1) ? kb : vb;
      float acc[4];
      float bb = bia[c];
      #pragma unroll
      for (int i = 0; i < 4; ++i) acc[i] = bb;
      const float* wp = W + c;
      #pragma unroll 2
      for (int k = 0; k < HH; k += 8) {
        float w[8];
        #pragma unroll
        for (int q = 0; q < 8; ++q) w[q] = wp[(size_t)(k + q) * HH];
        #pragma unroll
        for (int i = 0; i < 4; ++i) {
          const float4 a0 = *(const float4*)&As[wv * 4 + i][k];
          const float4 a1 = *(const float4*)&As[wv * 4 + i][k + 4];
          acc[i] = fmaf(a0.x, w[0], acc[i]);
          acc[i] = fmaf(a0.y, w[1], acc[i]);
          acc[i] = fmaf(a0.z, w[2], acc[i]);
          acc[i] = fmaf(a0.w, w[3], acc[i]);
          acc[i] = fmaf(a1.x, w[4], acc[i]);
          acc[i] = fmaf(a1.y, w[5], acc[i]);
          acc[i] = fmaf(a1.z, w[6], acc[i]);
          acc[i] = fmaf(a1.w, w[7], acc[i]);
        }
      }
      #pragma unroll
      for (int i = 0; i < 4; ++i)
        O[(size_t)(tok0 + wv * 4 + i) * HH + c] = acc[i];
    }
  } else {
    int o = (bid - QKV_END) * 256 + t;
    int cp = o / HH, cc = o - cp * HH;
    WrT[o] = Wr[(size_t)cc * HH + cp];
  }
}

// ---------------------------------------------------------------------------
// Generic tiled GEMM: C[M,N] = op(A[M,KK] @ W[KK,N] + bias)
// ---------------------------------------------------------------------------
template<int TT, int KK, bool RELU>
__global__ __launch_bounds__(256) void k_gemm(
    const float* __restrict__ A, const float* __restrict__ W,
    const float* __restrict__ bias, float* __restrict__ C, int N) {
  const int TPW = TT / 4;
  int tok0 = blockIdx.x * TT;
  int t = threadIdx.x;
  __shared__ __align__(16) float As[TT][KK];
  {
    const float4* src = (const float4*)(A + (size_t)tok0 * KK);
    float4* dst = (float4*)As;
    for (int idx = t; idx < TT * KK / 4; idx += 256) dst[idx] = src[idx];
  }
  __syncthreads();
  int c = (t & 63) + blockIdx.y * 64;
  int wv = t >> 6;
  if (c < N) {
    float acc[TPW];
    float bb = bias ? bias[c] : 0.0f;
    #pragma unroll
    for (int i = 0; i < TPW; ++i) acc[i] = bb;
    const float* wp = W + c;
    #pragma unroll 2
    for (int k = 0; k < KK; k += 8) {
      float w[8];
      #pragma unroll
      for (int q = 0; q < 8; ++q) w[q] = wp[(size_t)(k + q) * N];
      #pragma unroll
      for (int i = 0; i < TPW; ++i) {
        const float4 a0 = *(const float4*)&As[wv * TPW + i][k];
        const float4 a1 = *(const float4*)&As[wv * TPW + i][k + 4];
        acc[i] = fmaf(a0.x, w[0], acc[i]);
        acc[i] = fmaf(a0.y, w[1], acc[i]);
        acc[i] = fmaf(a0.z, w[2], acc[i]);
        acc[i] = fmaf(a0.w, w[3], acc[i]);
        acc[i] = fmaf(a1.x, w[4], acc[i]);
        acc[i] = fmaf(a1.y, w[5], acc[i]);
        acc[i] = fmaf(a1.z, w[6], acc[i]);
        acc[i] = fmaf(a1.w, w[7], acc[i]);
      }
    }
    #pragma unroll
    for (int i = 0; i < TPW; ++i) {
      float v = RELU ? fmaxf(acc[i], 0.0f) : acc[i];
      C[(size_t)(tok0 + wv * TPW + i) * N + c] = v;
    }
  }
}

// ---------------------------------------------------------------------------
// LN1 + W1 + relu fused.
// ---------------------------------------------------------------------------
__global__ __launch_bounds__(256) void k_ffn1(
    const float* __restrict__ Y, const float* __restrict__ g1,
    const float* __restrict__ b1ln, const float* __restrict__ W1,
    const float* __restrict__ b1, float* __restrict__ Hb) {
  const int TT = 16;
  int tok0 = blockIdx.x * TT;
  int t = threadIdx.x;
  __shared__ __align__(16) float As[TT][HH];
  {
    const float4* src = (const float4*)(Y + (size_t)tok0 * HH);
    float4* dst = (float4*)As;
    for (int idx = t; idx < TT * HH / 4; idx += 256) dst[idx] = src[idx];
  }
  __syncthreads();
  {
    int row = t >> 4, l = t & 15;
    float s = 0.0f;
    #pragma unroll
    for (int c = l; c < HH; c += 16) s += As[row][c];
    #pragma unroll
    for (int m = 1; m < 16; m <<= 1) s += __shfl_xor(s, m);
    float mu = s * (1.0f / HH);
    float s2 = 0.0f;
    #pragma unroll
    for (int c = l; c < HH; c += 16) { float d = As[row][c] - mu; s2 = fmaf(d, d, s2); }
    #pragma unroll
    for (int m = 1; m < 16; m <<= 1) s2 += __shfl_xor(s2, m);
    float rstd = rsqrtf(s2 * (1.0f / HH) + 2.5e-6f);  // eps 1e-5 / 4
    #pragma unroll
    for (int c = l; c < HH; c += 16)
      As[row][c] = (As[row][c] - mu) * rstd * g1[c] + b1ln[c];
  }
  __syncthreads();
  int c = (t & 63) + blockIdx.y * 64;
  int wv = t >> 6;
  float acc[4];
  float bb = b1[c];
  #pragma unroll
  for (int i = 0; i < 4; ++i) acc[i] = bb;
  const float* wp = W1 + c;
  #pragma unroll 2
  for (int k = 0; k < HH; k += 8) {
    float w[8];
    #pragma unroll
    for (int q = 0; q < 8; ++q) w[q] = wp[(size_t)(k + q) * FF_];
    #pragma unroll
    for (int i = 0; i < 4; ++i) {
      const float4 a0 = *(const float4*)&As[wv * 4 + i][k];
      const float4 a1 = *(const float4*)&As[wv * 4 + i][k + 4];
      acc[i] = fmaf(a0.x, w[0], acc[i]);
      acc[i] = fmaf(a0.y, w[1], acc[i]);
      acc[i] = fmaf(a0.z, w[2], acc[i]);
      acc[i] = fmaf(a0.w, w[3], acc[i]);
      acc[i] = fmaf(a1.x, w[4], acc[i]);
      acc[i] = fmaf(a1.y, w[5], acc[i]);
      acc[i] = fmaf(a1.z, w[6], acc[i]);
      acc[i] = fmaf(a1.w, w[7], acc[i]);
    }
  }
  #pragma unroll
  for (int i = 0; i < 4; ++i)
    Hb[(size_t)(tok0 + wv * 4 + i) * FF_ + c] = fmaxf(acc[i], 0.0f);
}

// ---------------------------------------------------------------------------
// Score kernel with bf16 P gather: each lane loads uint4 = 8 bf16 per tab
// per q5 step (5 steps cover 40 c's) -> half the loads/bytes of f32.
// grid 2048 = (b,i) x j-half; 256 threads.  Wave w handles tiles {w, 7-w}.
// ---------------------------------------------------------------------------
#define RSTR 164
#define SCP  132   // sc_s row stride

__global__ __launch_bounds__(256, 4) void k_score(
    const float* __restrict__ qb, const float* __restrict__ kb,
    const float* __restrict__ WrT, const __hip_bfloat16* __restrict__ Pbf,
    const int* __restrict__ pos_s, const int* __restrict__ pos_e,
    const int* __restrict__ seq_len, const int* __restrict__ lex_num,
    const float* __restrict__ utab, const float* __restrict__ vtab,
    float* __restrict__ scores) {
  int bid = blockIdx.x;
  int blk = bid >> 1;          // b*S + i
  int half = bid & 1;
  int b = blk >> 8;
  int i = blk & 255;
  int t = threadIdx.x;
  int limit = seq_len[b] + lex_num[0];
  if (half * 128 >= limit) return;   // whole half masked (uniform)

  __shared__ __align__(16) float qu[HH];
  __shared__ __align__(16) float qv_s[HH];
  __shared__ __align__(16) float g_s[NH_][RSTR];
  __shared__ __align__(16) float sc_s[NH_][SCP];
  __shared__ int ps_s[SS], pe_s[SS];

  if (t < HH) {
    float q = qb[(size_t)blk * HH + t];
    qu[t] = q + utab[t];
    qv_s[t] = q + vtab[t];
  }
  ps_s[t] = pos_s[b * SS + t];
  pe_s[t] = pos_e[b * SS + t];
  __syncthreads();

  // g[h][cc] = sum_d qv[20h+d] * WrT[(20h+d)*160+cc]
  #pragma unroll
  for (int r = 0; r < 5; ++r) {
    int p = r * 256 + t;
    int h = p / HH, cc = p - h * HH;
    const float* wp = WrT + (size_t)(h * HD_) * HH + cc;
    float acc = 0.0f;
    #pragma unroll
    for (int d = 0; d < HD_; ++d)
      acc = fmaf(qv_s[h * HD_ + d], wp[(size_t)d * HH], acc);
    g_s[h][cc] = acc;
  }
  __syncthreads();

  int w = t >> 6, lane = t & 63;
  int jj = lane >> 2, cg = lane & 3;
  int psi = ps_s[i], pei = pe_s[i];
  const float scale = 0.22360679774997896f;  // 1/sqrt(20)

  // bf16 planes: row stride = 160*2B = 20 uint4; plane = 512 rows.
  const uint4* Pb0 = (const uint4*)Pbf;
  const uint4* Pb1 = Pb0 + (size_t)PROWS * 20;
  const uint4* Pb2 = Pb1 + (size_t)PROWS * 20;
  const uint4* Pb3 = Pb2 + (size_t)PROWS * 20;
  const float4* kb4 = (const float4*)(kb + (size_t)b * SS * HH);

  #pragma unroll
  for (int pass = 0; pass < 2; ++pass) {
    int tau = (pass == 0) ? w : 7 - w;
    int jl = tau * 16 + jj;          // 0..127
    int j = half * 128 + jl;
    if (half * 128 + tau * 16 >= limit) continue;   // tile fully masked
    int psj = ps_s[j], pej = pe_s[j];
    int r0b = (psi - psj + 256) * 20;
    int r1b = (psi - pej + 256) * 20;
    int r2b = (pei - psj + 256) * 20;
    int r3b = (pei - pej + 256) * 20;
    float bd[NH_];
    #pragma unroll
    for (int h = 0; h < NH_; ++h) bd[h] = 0.0f;
    // gather: 4 uint4 (32 bf16) -> unpack -> relu -> 64 FMAs, per q5
    #pragma unroll 2
    for (int q5 = 0; q5 < 5; ++q5) {
      int off = q5 * 4 + cg;
      uint4 u0 = Pb0[r0b + off];
      uint4 u1 = Pb1[r1b + off];
      uint4 u2 = Pb2[r2b + off];
      uint4 u3 = Pb3[r3b + off];
      float rl[8];
      rl[0] = fmaxf(blo(u0.x) + blo(u1.x) + blo(u2.x) + blo(u3.x), 0.0f);
      rl[1] = fmaxf(bhi(u0.x) + bhi(u1.x) + bhi(u2.x) + bhi(u3.x), 0.0f);
      rl[2] = fmaxf(blo(u0.y) + blo(u1.y) + blo(u2.y) + blo(u3.y), 0.0f);
      rl[3] = fmaxf(bhi(u0.y) + bhi(u1.y) + bhi(u2.y) + bhi(u3.y), 0.0f);
      rl[4] = fmaxf(blo(u0.z) + blo(u1.z) + blo(u2.z) + blo(u3.z), 0.0f);
      rl[5] = fmaxf(bhi(u0.z) + bhi(u1.z) + bhi(u2.z) + bhi(u3.z), 0.0f);
      rl[6] = fmaxf(blo(u0.w) + blo(u1.w) + blo(u2.w) + blo(u3.w), 0.0f);
      rl[7] = fmaxf(bhi(u0.w) + bhi(u1.w) + bhi(u2.w) + bhi(u3.w), 0.0f);
      int cb = off * 8;
      #pragma unroll
      for (int h = 0; h < NH_; ++h) {
        float4 ga = *(const float4*)&g_s[h][cb];
        float4 gb = *(const float4*)&g_s[h][cb + 4];
        bd[h] = fmaf(rl[0], ga.x, bd[h]);
        bd[h] = fmaf(rl[1], ga.y, bd[h]);
        bd[h] = fmaf(rl[2], ga.z, bd[h]);
        bd[h] = fmaf(rl[3], ga.w, bd[h]);
        bd[h] = fmaf(rl[4], gb.x, bd[h]);
        bd[h] = fmaf(rl[5], gb.y, bd[h]);
        bd[h] = fmaf(rl[6], gb.z, bd[h]);
        bd[h] = fmaf(rl[7], gb.w, bd[h]);
      }
    }
    // A_C for heads 2cg, 2cg+1 : c in [40cg, 40cg+40)
    float ac0 = 0.0f, ac1 = 0.0f;
    {
      int kbase = j * 40 + 10 * cg;
      #pragma unroll
      for (int m = 0; m < 10; ++m) {
        float4 kv = kb4[kbase + m];
        float4 q4 = *(const float4*)&qu[(10 * cg + m) * 4];
        if (m < 5) {
          ac0 = fmaf(q4.x, kv.x, ac0); ac0 = fmaf(q4.y, kv.y, ac0);
          ac0 = fmaf(q4.z, kv.z, ac0); ac0 = fmaf(q4.w, kv.w, ac0);
        } else {
          ac1 = fmaf(q4.x, kv.x, ac1); ac1 = fmaf(q4.y, kv.y, ac1);
          ac1 = fmaf(q4.z, kv.z, ac1); ac1 = fmaf(q4.w, kv.w, ac1);
        }
      }
    }
    // reduce bd over the 4 cg lanes
    #pragma unroll
    for (int h = 0; h < NH_; ++h) {
      bd[h] += __shfl_xor(bd[h], 1);
      bd[h] += __shfl_xor(bd[h], 2);
    }
    float s0, s1;
    if      (cg == 0) { s0 = bd[0]; s1 = bd[1]; }
    else if (cg == 1) { s0 = bd[2]; s1 = bd[3]; }
    else if (cg == 2) { s0 = bd[4]; s1 = bd[5]; }
    else              { s0 = bd[6]; s1 = bd[7]; }
    sc_s[2 * cg][jl]     = (s0 + ac0) * scale;
    sc_s[2 * cg + 1][jl] = (s1 + ac1) * scale;
  }
  __syncthreads();

  // coalesced writeout: 8 rows x 32 float4
  {
    int row = t >> 5, c4 = t & 31;
    float4 v = *(const float4*)&sc_s[row][c4 * 4];
    *(float4*)&scores[((size_t)blk * NH_ + row) * SS + half * 128 + c4 * 4] = v;
  }
}

// ---------------------------------------------------------------------------
// Softmax + PV kernel: grid 1024, 256 threads.
// ---------------------------------------------------------------------------
#define SCS 260

__global__ __launch_bounds__(256, 4) void k_smpv(
    const float* __restrict__ scores, const float* __restrict__ vb,
    const int* __restrict__ seq_len, const int* __restrict__ lex_num,
    float* __restrict__ attn_out) {
  int blk = blockIdx.x;
  int b = blk >> 8;
  int t = threadIdx.x;
  __shared__ __align__(16) float sc[NH_][SCS];
  int limit = seq_len[b] + lex_num[0];

  const float4* src = (const float4*)(scores + (size_t)blk * NH_ * SS);
  #pragma unroll
  for (int r = 0; r < 2; ++r) {
    int idx = r * 256 + t;
    int row = idx >> 6, c4 = idx & 63;
    float4 v = src[idx];
    int j0 = c4 * 4;
    v.x = (j0 + 0 < limit) ? v.x : -1.0e15f;
    v.y = (j0 + 1 < limit) ? v.y : -1.0e15f;
    v.z = (j0 + 2 < limit) ? v.z : -1.0e15f;
    v.w = (j0 + 3 < limit) ? v.w : -1.0e15f;
    *(float4*)&sc[row][j0] = v;
  }
  __syncthreads();

  {
    int h = t >> 5, l = t & 31;
    float m = -3.0e38f;
    float e[8];
    #pragma unroll
    for (int ii = 0; ii < 8; ++ii) m = fmaxf(m, sc[h][l + ii * 32]);
    #pragma unroll
    for (int msk = 16; msk; msk >>= 1) m = fmaxf(m, __shfl_xor(m, msk));
    float s = 0.0f;
    #pragma unroll
    for (int ii = 0; ii < 8; ++ii) { e[ii] = __expf(sc[h][l + ii * 32] - m); s += e[ii]; }
    #pragma unroll
    for (int msk = 16; msk; msk >>= 1) s += __shfl_xor(s, msk);
    float inv = 1.0f / s;
    #pragma unroll
    for (int ii = 0; ii < 8; ++ii) sc[h][l + ii * 32] = e[ii] * inv;
  }
  __syncthreads();

  if (t < HH) {
    int h = t / HD_;
    int lim4 = (limit + 3) & ~3;
    float acc0 = 0.f, acc1 = 0.f, acc2 = 0.f, acc3 = 0.f;
    const float* vcol = vb + (size_t)b * SS * HH + t;
    for (int j2 = 0; j2 < lim4; j2 += 4) {
      float4 p4 = *(const float4*)&sc[h][j2];
      acc0 = fmaf(p4.x, vcol[(size_t)(j2 + 0) * HH], acc0);
      acc1 = fmaf(p4.y, vcol[(size_t)(j2 + 1) * HH], acc1);
      acc2 = fmaf(p4.z, vcol[(size_t)(j2 + 2) * HH], acc2);
      acc3 = fmaf(p4.w, vcol[(size_t)(j2 + 3) * HH], acc3);
    }
    attn_out[(size_t)blk * HH + t] = (acc0 + acc1) + (acc2 + acc3);
  }
}

// ---------------------------------------------------------------------------
// Final LayerNorm.  LN(y+y) == LN(y) with eps/4.
// ---------------------------------------------------------------------------
__global__ __launch_bounds__(256) void k_ln(
    const float* __restrict__ Y, const float* __restrict__ g,
    const float* __restrict__ bln, float* __restrict__ O) {
  int tok = blockIdx.x * 4 + (threadIdx.x >> 6);
  int l = threadIdx.x & 63;
  const float* y = Y + (size_t)tok * HH;
  float a = y[l];
  float bv = y[l + 64];
  bool has3 = l < (HH - 128);
  float cv = has3 ? y[l + 128] : 0.0f;
  float s = a + bv + cv;
  #pragma unroll
  for (int m = 32; m; m >>= 1) s += __shfl_xor(s, m);
  float mu = s * (1.0f / HH);
  float da = a - mu, db = bv - mu, dc = has3 ? (cv - mu) : 0.0f;
  float s2 = da * da + db * db + dc * dc;
  #pragma unroll
  for (int m = 32; m; m >>= 1) s2 += __shfl_xor(s2, m);
  float rstd = rsqrtf(s2 * (1.0f / HH) + 2.5e-6f);  // eps 1e-5 / 4
  float* o = O + (size_t)tok * HH;
  o[l]      = da * rstd * g[l] + bln[l];
  o[l + 64] = db * rstd * g[l + 64] + bln[l + 64];
  if (has3) o[l + 128] = dc * rstd * g[l + 128] + bln[l + 128];
}

// ---------------------------------------------------------------------------
extern "C" void kernel_launch(void* const* d_in, const int* in_sizes, int n_in,
                              void* d_out, int out_size, void* d_ws, size_t ws_size,
                              hipStream_t stream) {
  const float* inp    = (const float*)d_in[0];
  const int*   pos_s  = (const int*)d_in[1];
  const int*   pos_e  = (const int*)d_in[2];
  const int*   seq_ln = (const int*)d_in[3];
  const int*   lex_nm = (const int*)d_in[4];
  const float* pe_ss  = (const float*)d_in[5];
  const float* pe_se  = (const float*)d_in[6];
  const float* pe_es  = (const float*)d_in[7];
  const float* pe_ee  = (const float*)d_in[8];
  const float* W_fus  = (const float*)d_in[9];
  const float* b_fus  = (const float*)d_in[10];
  const float* Wq     = (const float*)d_in[11];
  const float* bq     = (const float*)d_in[12];
  const float* Wk     = (const float*)d_in[13];
  const float* bk     = (const float*)d_in[14];
  const float* Wv     = (const float*)d_in[15];
  const float* bv     = (const float*)d_in[16];
  const float* Wr     = (const float*)d_in[17];
  // d_in[18] = br : constant-over-j term, cancels in softmax
  const float* utab   = (const float*)d_in[19];
  const float* vtab   = (const float*)d_in[20];
  const float* W_fin  = (const float*)d_in[21];
  const float* b_fin  = (const float*)d_in[22];
  const float* ln1_g  = (const float*)d_in[23];
  const float* ln1_b  = (const float*)d_in[24];
  const float* W1     = (const float*)d_in[25];
  const float* b1     = (const float*)d_in[26];
  const float* W2     = (const float*)d_in[27];
  const float* b2     = (const float*)d_in[28];
  const float* ln2_g  = (const float*)d_in[29];
  const float* ln2_b  = (const float*)d_in[30];

  float* ws = (float*)d_ws;
  __hip_bfloat16* Pbf = (__hip_bfloat16*)ws;   // 4*512*160 bf16 = 655360 B
  float* qb       = ws + 163840;               // (bf16 region = 163840 floats)
  float* kb       = qb + BB * SS * HH;
  float* vb       = kb + BB * SS * HH;
  float* WrT      = vb + BB * SS * HH;         // 25600
  float* attn_out = WrT + HH * HH;             // 163840
  float* scores   = attn_out + BB * SS * HH;   // 2097152 (1024*8*256)
  // scores dead after k_smpv; alias FFN buffers:
  float* ybuf     = scores;
  float* hbuf     = scores + 163840;
  float* y2       = scores + 819200;

  (void)in_sizes; (void)n_in; (void)out_size; (void)ws_size;

  const int M = BB * SS;  // 1024

  k_setup<<<WRT_END, 256, 0, stream>>>(pe_ss, pe_se, pe_es, pe_ee, W_fus, b_fus,
                                       inp, Wq, bq, Wk, bk, Wv, bv, Wr,
                                       Pbf, qb, kb, vb, WrT);
  k_score<<<2 * M, 256, 0, stream>>>(qb, kb, WrT, Pbf, pos_s, pos_e, seq_ln, lex_nm,
                                     utab, vtab, scores);
  k_smpv<<<M, 256, 0, stream>>>(scores, vb, seq_ln, lex_nm, attn_out);
  k_gemm<4, HH, false><<<dim3(M / 4, 3), 256, 0, stream>>>(attn_out, W_fin, b_fin, ybuf, HH);
  k_ffn1<<<dim3(M / 16, 10), 256, 0, stream>>>(ybuf, ln1_g, ln1_b, W1, b1, hbuf);
  k_gemm<4, FF_, false><<<dim3(M / 4, 3), 256, 0, stream>>>(hbuf, W2, b2, y2, HH);
  k_ln<<<M / 4, 256, 0, stream>>>(y2, ln2_g, ln2_b, (float*)d_out);
}